// Round 6
// baseline (1454.528 us; speedup 1.0000x reference)
//
#include <hip/hip_runtime.h>

#define NN 50000
#define NE 1000000
#define NG 1000
#define KE 147
#define DH 128
#define CH 125056   // layer0 chunk rows (= 977*128)

using u16 = unsigned short;
typedef __attribute__((ext_vector_type(8))) short bf16x8;
typedef __attribute__((ext_vector_type(4))) float f32x4;

__device__ __forceinline__ float lrelu(float v){ return fmaxf(v, 0.01f*v); }
__device__ __forceinline__ float bf2f(u16 u){ unsigned int x = ((unsigned int)u)<<16; float f; __builtin_memcpy(&f,&x,4); return f; }
__device__ __forceinline__ u16 f2bf(float f){ unsigned int x; __builtin_memcpy(&x,&f,4); x += 0x7fffu + ((x>>16)&1u); return (u16)(x>>16); }
__device__ __forceinline__ float bflo(unsigned w){ unsigned x = w<<16; float f; __builtin_memcpy(&f,&x,4); return f; }
__device__ __forceinline__ float bfhi(unsigned w){ unsigned x = w & 0xffff0000u; float f; __builtin_memcpy(&f,&x,4); return f; }
__device__ __forceinline__ unsigned pk2(float lo, float hi){ return ((unsigned)f2bf(hi)<<16) | (unsigned)f2bf(lo); }
// column permutation: memory position p holds logical column cpi(p)
__device__ __host__ __forceinline__ int cpi(int p){ return (p & 64) | ((p & 3) << 4) | ((p & 63) >> 2); }

// ================= CSR build =================
__global__ __launch_bounds__(256) void hist_kernel(const int* __restrict__ endi, const int* __restrict__ srt,
                                                   int* __restrict__ cntE, int* __restrict__ cntS){
  for (int i = blockIdx.x*256 + threadIdx.x; i < NE; i += gridDim.x*256){
    atomicAdd(&cntE[endi[i]], 1);
    atomicAdd(&cntS[srt[i]], 1);
  }
}

__global__ __launch_bounds__(1024) void scan2_kernel(const int* __restrict__ cntE, int* __restrict__ offE,
                                                     const int* __restrict__ cntS, int* __restrict__ offS){
  const int* deg = blockIdx.x ? cntS : cntE;
  int* off = blockIdx.x ? offS : offE;
  __shared__ int wsum[17];
  const int t = threadIdx.x, lane = t & 63, wv = t >> 6;
  int carry = 0;
  for (int base = 0; base < 50176; base += 1024){
    const int i = base + t;
    int v = (i < NN) ? deg[i] : 0;
    int s = v;
    #pragma unroll
    for (int d = 1; d < 64; d <<= 1){
      int x = __shfl_up(s, d);
      if (lane >= d) s += x;
    }
    if (lane == 63) wsum[wv] = s;
    __syncthreads();
    if (t == 0){
      int run = 0;
      #pragma unroll
      for (int k = 0; k < 16; ++k){ int x = wsum[k]; wsum[k] = run; run += x; }
      wsum[16] = run;
    }
    __syncthreads();
    if (i <= NN) off[i] = carry + wsum[wv] + s - v;
    carry += wsum[16];
    __syncthreads();
  }
}

// scatter: rankE (edge->permuted row), srtE (per row), listS2 (srt-CSR -> permuted row), endS
__global__ __launch_bounds__(256) void scatter_kernel(const int* __restrict__ endi, const int* __restrict__ srt,
                                                      int* __restrict__ curE, int* __restrict__ curS,
                                                      int* __restrict__ rankE, int* __restrict__ srtE,
                                                      int* __restrict__ listS2, int* __restrict__ endS){
  for (int i = blockIdx.x*256 + threadIdx.x; i < NE; i += gridDim.x*256){
    const int e = endi[i], s = srt[i];
    int p = atomicAdd(&curE[e], 1);
    rankE[i] = p; srtE[p] = s;
    int q = atomicAdd(&curS[s], 1);
    listS2[q] = p; endS[q] = e;
  }
}

// Wb0: natural layout padded K=160. Wb1: K permuted by cpi. bp0/bp1: biases permuted by cpi.
__global__ __launch_bounds__(256) void convertW_kernel(const float* __restrict__ W1, const float* __restrict__ W0,
                                                       const float* __restrict__ b0, const float* __restrict__ b1,
                                                       u16* __restrict__ Wb1, u16* __restrict__ Wb0,
                                                       float* __restrict__ bp0, float* __restrict__ bp1){
  int i = blockIdx.x*256 + threadIdx.x;
  if (i < 128*128){
    int j = i >> 7, k = i & 127;
    Wb1[i] = f2bf(W1[j*DH + cpi(k)]);
  }
  if (i < 128*160){
    int j = i/160, k = i - j*160;
    Wb0[i] = (k < KE) ? f2bf(W0[j*KE + k]) : (u16)0;
  }
  if (i < 128){ bp0[i] = b0[cpi(i)]; bp1[i] = b1[cpi(i)]; }
}

// ================= cf (f32, K=147) -> cfb (bf16, K=160 padded), rows [lo,hi) =================
__global__ __launch_bounds__(256) void cvt_cf(const float* __restrict__ cf, u16* __restrict__ cfb,
                                              int lo, int hi){
  const int total = (hi - lo) * 20;
  for (int idx = blockIdx.x*256 + threadIdx.x; idx < total; idx += gridDim.x*256){
    const int r = idx / 20, g = idx - r*20;
    const float* rp = cf + (size_t)(lo + r)*KE;
    const int c0 = g*8;
    u16 o[8];
    #pragma unroll
    for (int j = 0; j < 8; ++j){
      const int c = c0 + j;
      o[j] = (c < KE) ? f2bf(rp[c]) : (u16)0;
    }
    *(uint4*)&cfb[(size_t)r*160 + c0] = *(const uint4*)o;
  }
}

// ================= layer 0 GEMM: h'[rankE[e]] = lrelu(cfb[e] @ W0^T + b) — no LDS, aligned loads =====
__global__ __launch_bounds__(256) void layer0_gemm(const u16* __restrict__ cfb, const u16* __restrict__ Wb0,
                                                   const float* __restrict__ bp0, const int* __restrict__ rankE,
                                                   u16* __restrict__ h, int lo, int hi){
  const int t = threadIdx.x, lane = t & 63, wv = t >> 6;
  const int wr = wv >> 1, wc = wv & 1;
  const int e0 = lo + blockIdx.x*128;
  const int q = lane & 15, kg8 = (lane >> 4)*8;

  bf16x8 bfrag[5][4];
  #pragma unroll
  for (int fc = 0; fc < 4; ++fc)
    #pragma unroll
    for (int ks = 0; ks < 5; ++ks)
      bfrag[ks][fc] = *(const bf16x8*)&Wb0[(size_t)(wc*64 + fc*16 + q)*160 + ks*32 + kg8];

  f32x4 acc[4][4];
  #pragma unroll
  for (int fr = 0; fr < 4; ++fr)
    #pragma unroll
    for (int fc = 0; fc < 4; ++fc){ acc[fr][fc][0]=0.f; acc[fr][fc][1]=0.f; acc[fr][fc][2]=0.f; acc[fr][fc][3]=0.f; }

  #pragma unroll
  for (int ks = 0; ks < 5; ++ks){
    bf16x8 a[4];
    #pragma unroll
    for (int fr = 0; fr < 4; ++fr){
      const int e = e0 + wr*64 + fr*16 + q;
      if (e < hi) a[fr] = *(const bf16x8*)&cfb[(size_t)(e - lo)*160 + ks*32 + kg8];
      else { bf16x8 z = {0,0,0,0,0,0,0,0}; a[fr] = z; }
    }
    #pragma unroll
    for (int fr = 0; fr < 4; ++fr)
      #pragma unroll
      for (int fc = 0; fc < 4; ++fc)
        acc[fr][fc] = __builtin_amdgcn_mfma_f32_16x16x32_bf16(a[fr], bfrag[ks][fc], acc[fr][fc], 0, 0, 0);
  }

  const float4 bb = *(const float4*)&bp0[wc*64 + q*4];
  #pragma unroll
  for (int fr = 0; fr < 4; ++fr){
    #pragma unroll
    for (int r = 0; r < 4; ++r){
      const int ee = e0 + wr*64 + fr*16 + (lane>>4)*4 + r;
      if (ee < hi){
        const int row = rankE[ee];
        ushort4 o;
        o.x = f2bf(lrelu(acc[fr][0][r] + bb.x));
        o.y = f2bf(lrelu(acc[fr][1][r] + bb.y));
        o.z = f2bf(lrelu(acc[fr][2][r] + bb.z));
        o.w = f2bf(lrelu(acc[fr][3][r] + bb.w));
        *(ushort4*)&h[(size_t)row*DH + wc*64 + q*4] = o;
      }
    }
  }
}

// ================= agg[n] = sum of h' rows [offE[n], offE[n+1]) — 4-way ILP =================
__global__ __launch_bounds__(256) void aggE_kernel(const u16* __restrict__ h, const int* __restrict__ off,
                                                   float* __restrict__ agg){
  const int t = threadIdx.x, lane = t & 63, wv = t >> 6;
  const int n = blockIdx.x*4 + wv;
  if (n >= NN) return;
  const int lo = off[n], hi = off[n+1];
  const int c8 = (lane & 15)*8, sub = lane >> 4;
  float a0=0,a1=0,a2=0,a3=0,a4=0,a5=0,a6=0,a7=0;
  for (int i = lo + sub; i < hi; i += 4){
    uint4 hv = *(const uint4*)&h[(size_t)i*DH + c8];
    a0 += bflo(hv.x); a1 += bfhi(hv.x); a2 += bflo(hv.y); a3 += bfhi(hv.y);
    a4 += bflo(hv.z); a5 += bfhi(hv.z); a6 += bflo(hv.w); a7 += bfhi(hv.w);
  }
  a0 += __shfl_xor(a0,16); a1 += __shfl_xor(a1,16); a2 += __shfl_xor(a2,16); a3 += __shfl_xor(a3,16);
  a4 += __shfl_xor(a4,16); a5 += __shfl_xor(a5,16); a6 += __shfl_xor(a6,16); a7 += __shfl_xor(a7,16);
  a0 += __shfl_xor(a0,32); a1 += __shfl_xor(a1,32); a2 += __shfl_xor(a2,32); a3 += __shfl_xor(a3,32);
  a4 += __shfl_xor(a4,32); a5 += __shfl_xor(a5,32); a6 += __shfl_xor(a6,32); a7 += __shfl_xor(a7,32);
  if (sub == 0){
    *(float4*)&agg[(size_t)n*DH + c8]     = make_float4(a0,a1,a2,a3);
    *(float4*)&agg[(size_t)n*DH + c8 + 4] = make_float4(a4,a5,a6,a7);
  }
}

// ================= P/Q GEMM: P = agg@W^T + b ; Q = h'[rankE[0:N]]@W^T  (pi space in/out) =====
__global__ __launch_bounds__(256) void pq_gemm(const float* __restrict__ agg, const u16* __restrict__ h,
                                               const int* __restrict__ rankE, const u16* __restrict__ Wb1,
                                               const float* __restrict__ bp1, float* __restrict__ P,
                                               float* __restrict__ Q){
  __shared__ u16 Alds[128][136];
  const int t = threadIdx.x, lane = t & 63, wv = t >> 6;
  const int wr = wv >> 1, wc = wv & 1;
  const int r0 = blockIdx.x * 128;
  const int q = lane & 15, kg8 = (lane >> 4)*8;

  bf16x8 bfrag[4][4];
  #pragma unroll
  for (int fc = 0; fc < 4; ++fc)
    #pragma unroll
    for (int ks = 0; ks < 4; ++ks)
      bfrag[ks][fc] = *(const bf16x8*)&Wb1[(size_t)(wc*64 + fc*16 + q)*128 + ks*32 + kg8];

  {
    const int rt = t >> 1, half = t & 1;
    const int gr = r0 + rt;
    u16* dst = &Alds[rt][half*64];
    if (gr < NN){
      const float4* src = (const float4*)&agg[(size_t)gr*DH + half*64];
      #pragma unroll
      for (int p = 0; p < 16; ++p){
        float4 x = src[p];
        ushort4 o; o.x=f2bf(x.x); o.y=f2bf(x.y); o.z=f2bf(x.z); o.w=f2bf(x.w);
        *(ushort4*)&dst[p*4] = o;
      }
    } else if (gr < 2*NN){
      const int row = rankE[gr - NN];
      const ushort4* src = (const ushort4*)&h[(size_t)row*DH + half*64];
      #pragma unroll
      for (int p = 0; p < 16; ++p) *(ushort4*)&dst[p*4] = src[p];
    } else {
      ushort4 z; z.x=0; z.y=0; z.z=0; z.w=0;
      #pragma unroll
      for (int p = 0; p < 16; ++p) *(ushort4*)&dst[p*4] = z;
    }
  }
  __syncthreads();

  f32x4 acc[4][4];
  #pragma unroll
  for (int fr = 0; fr < 4; ++fr)
    #pragma unroll
    for (int fc = 0; fc < 4; ++fc){ acc[fr][fc][0]=0.f; acc[fr][fc][1]=0.f; acc[fr][fc][2]=0.f; acc[fr][fc][3]=0.f; }
  #pragma unroll
  for (int ks = 0; ks < 4; ++ks){
    bf16x8 a[4];
    #pragma unroll
    for (int fr = 0; fr < 4; ++fr)
      a[fr] = *(const bf16x8*)&Alds[wr*64 + fr*16 + q][ks*32 + kg8];
    #pragma unroll
    for (int fr = 0; fr < 4; ++fr)
      #pragma unroll
      for (int fc = 0; fc < 4; ++fc)
        acc[fr][fc] = __builtin_amdgcn_mfma_f32_16x16x32_bf16(a[fr], bfrag[ks][fc], acc[fr][fc], 0, 0, 0);
  }

  const float4 bb = *(const float4*)&bp1[wc*64 + q*4];
  #pragma unroll
  for (int fr = 0; fr < 4; ++fr){
    #pragma unroll
    for (int r = 0; r < 4; ++r){
      const int grow = r0 + wr*64 + fr*16 + (lane>>4)*4 + r;
      if (grow < NN){
        float4 val = make_float4(acc[fr][0][r] + bb.x, acc[fr][1][r] + bb.y,
                                 acc[fr][2][r] + bb.z, acc[fr][3][r] + bb.w);
        *(float4*)&P[(size_t)grow*DH + wc*64 + q*4] = val;
      } else if (grow < 2*NN){
        float4 val = make_float4(acc[fr][0][r], acc[fr][1][r], acc[fr][2][r], acc[fr][3][r]);
        *(float4*)&Q[(size_t)(grow-NN)*DH + wc*64 + q*4] = val;
      }
    }
  }
}

// ===== middle layers: h'[i] = lrelu(h'[i] + P[srtE[i]] - Q[n]); agg[n]=sum — 4-way ILP =====
__global__ __launch_bounds__(256) void fused_mid(u16* __restrict__ h, const float* __restrict__ P,
                                                 const float* __restrict__ Q, const int* __restrict__ srtE,
                                                 const int* __restrict__ off, float* __restrict__ agg){
  const int t = threadIdx.x, lane = t & 63, wv = t >> 6;
  const int n = blockIdx.x*4 + wv;
  if (n >= NN) return;
  const int lo = off[n], hi = off[n+1];
  const int c8 = (lane & 15)*8, sub = lane >> 4;
  const float4 q0 = *(const float4*)&Q[(size_t)n*DH + c8];
  const float4 q1 = *(const float4*)&Q[(size_t)n*DH + c8 + 4];
  float a0=0,a1=0,a2=0,a3=0,a4=0,a5=0,a6=0,a7=0;
  for (int i = lo + sub; i < hi; i += 4){
    const int s = srtE[i];
    uint4 hv = *(const uint4*)&h[(size_t)i*DH + c8];
    float4 p0 = *(const float4*)&P[(size_t)s*DH + c8];
    float4 p1 = *(const float4*)&P[(size_t)s*DH + c8 + 4];
    float v0 = lrelu(bflo(hv.x) + p0.x - q0.x);
    float v1 = lrelu(bfhi(hv.x) + p0.y - q0.y);
    float v2 = lrelu(bflo(hv.y) + p0.z - q0.z);
    float v3 = lrelu(bfhi(hv.y) + p0.w - q0.w);
    float v4 = lrelu(bflo(hv.z) + p1.x - q1.x);
    float v5 = lrelu(bfhi(hv.z) + p1.y - q1.y);
    float v6 = lrelu(bflo(hv.w) + p1.z - q1.z);
    float v7 = lrelu(bfhi(hv.w) + p1.w - q1.w);
    uint4 o;
    o.x = pk2(v0, v1); o.y = pk2(v2, v3); o.z = pk2(v4, v5); o.w = pk2(v6, v7);
    *(uint4*)&h[(size_t)i*DH + c8] = o;
    a0+=v0; a1+=v1; a2+=v2; a3+=v3; a4+=v4; a5+=v5; a6+=v6; a7+=v7;
  }
  a0 += __shfl_xor(a0,16); a1 += __shfl_xor(a1,16); a2 += __shfl_xor(a2,16); a3 += __shfl_xor(a3,16);
  a4 += __shfl_xor(a4,16); a5 += __shfl_xor(a5,16); a6 += __shfl_xor(a6,16); a7 += __shfl_xor(a7,16);
  a0 += __shfl_xor(a0,32); a1 += __shfl_xor(a1,32); a2 += __shfl_xor(a2,32); a3 += __shfl_xor(a3,32);
  a4 += __shfl_xor(a4,32); a5 += __shfl_xor(a5,32); a6 += __shfl_xor(a6,32); a7 += __shfl_xor(a7,32);
  if (sub == 0){
    *(float4*)&agg[(size_t)n*DH + c8]     = make_float4(a0,a1,a2,a3);
    *(float4*)&agg[(size_t)n*DH + c8 + 4] = make_float4(a4,a5,a6,a7);
  }
}

// ===== last layer: hnode[s] = sum over srt-CSR of lrelu(h'[listS2[i]] + P[s] - Q[endS[i]]) — 4-way =====
__global__ __launch_bounds__(256) void fused_last(const u16* __restrict__ h, const float* __restrict__ P,
                                                  const float* __restrict__ Q, const int* __restrict__ endS,
                                                  const int* __restrict__ listS2, const int* __restrict__ off,
                                                  float* __restrict__ hnode){
  const int t = threadIdx.x, lane = t & 63, wv = t >> 6;
  const int s = blockIdx.x*4 + wv;
  if (s >= NN) return;
  const int lo = off[s], hi = off[s+1];
  const int c8 = (lane & 15)*8, sub = lane >> 4;
  const float4 p0 = *(const float4*)&P[(size_t)s*DH + c8];
  const float4 p1 = *(const float4*)&P[(size_t)s*DH + c8 + 4];
  float a0=0,a1=0,a2=0,a3=0,a4=0,a5=0,a6=0,a7=0;
  for (int i = lo + sub; i < hi; i += 4){
    const int row = listS2[i];
    const int d = endS[i];
    uint4 hv = *(const uint4*)&h[(size_t)row*DH + c8];
    float4 q0 = *(const float4*)&Q[(size_t)d*DH + c8];
    float4 q1 = *(const float4*)&Q[(size_t)d*DH + c8 + 4];
    a0 += lrelu(bflo(hv.x) + p0.x - q0.x);
    a1 += lrelu(bfhi(hv.x) + p0.y - q0.y);
    a2 += lrelu(bflo(hv.y) + p0.z - q0.z);
    a3 += lrelu(bfhi(hv.y) + p0.w - q0.w);
    a4 += lrelu(bflo(hv.z) + p1.x - q1.x);
    a5 += lrelu(bfhi(hv.z) + p1.y - q1.y);
    a6 += lrelu(bflo(hv.w) + p1.z - q1.z);
    a7 += lrelu(bfhi(hv.w) + p1.w - q1.w);
  }
  a0 += __shfl_xor(a0,16); a1 += __shfl_xor(a1,16); a2 += __shfl_xor(a2,16); a3 += __shfl_xor(a3,16);
  a4 += __shfl_xor(a4,16); a5 += __shfl_xor(a5,16); a6 += __shfl_xor(a6,16); a7 += __shfl_xor(a7,16);
  a0 += __shfl_xor(a0,32); a1 += __shfl_xor(a1,32); a2 += __shfl_xor(a2,32); a3 += __shfl_xor(a3,32);
  a4 += __shfl_xor(a4,32); a5 += __shfl_xor(a5,32); a6 += __shfl_xor(a6,32); a7 += __shfl_xor(a7,32);
  if (sub == 0){
    *(float4*)&hnode[(size_t)s*DH + c8]     = make_float4(a0,a1,a2,a3);
    *(float4*)&hnode[(size_t)s*DH + c8 + 4] = make_float4(a4,a5,a6,a7);
  }
}

// ================= nodes: atom = lrelu(hnode @ Wmol^T + b); normed = atom/||atom|| =================
// hnode columns are pi-permuted; permute Wmol's K during staging. Outputs canonical.
__global__ __launch_bounds__(256) void node_kernel(
    const float* __restrict__ hn, const float* __restrict__ W,
    const float* __restrict__ b, float* __restrict__ atom, float* __restrict__ normed)
{
  __shared__ float Wt[64*132];
  __shared__ float ms[32*DH];
  const int t = threadIdx.x;
  const int r0 = blockIdx.x * 32;
  const int jg = t & 31, eg = t >> 5;
  for (int idx = t; idx < 32*DH; idx += 256) {
    const int r = r0 + (idx >> 7);
    ms[idx] = (r < NN) ? hn[(size_t)r*DH + (idx & 127)] : 0.f;
  }
  float acc[4][4] = {};
  for (int c = 0; c < 2; ++c) {
    __syncthreads();
    for (int idx = t; idx < 128*64; idx += 256) {
      const int j = idx >> 6, kl = idx & 63;
      Wt[kl*132 + j] = W[j*DH + c*64 + ((kl&3)*16 + (kl>>2))];   // pi64 on K
    }
    __syncthreads();
    #pragma unroll 4
    for (int kl = 0; kl < 64; ++kl) {
      const float4 w = *(const float4*)&Wt[kl*132 + jg*4];
      const int kg = c*64 + kl;
      #pragma unroll
      for (int i = 0; i < 4; ++i) {
        const float mv = ms[(eg*4+i)*DH + kg];
        acc[i][0] += mv*w.x; acc[i][1] += mv*w.y; acc[i][2] += mv*w.z; acc[i][3] += mv*w.w;
      }
    }
  }
  float bj[4];
  #pragma unroll
  for (int c2 = 0; c2 < 4; ++c2) bj[c2] = b[jg*4 + c2];
  #pragma unroll
  for (int i = 0; i < 4; ++i) {
    const int r = r0 + eg*4 + i;
    float v[4]; float ss = 0.f;
    #pragma unroll
    for (int c2 = 0; c2 < 4; ++c2) { v[c2] = lrelu(acc[i][c2] + bj[c2]); ss += v[c2]*v[c2]; }
    ss += __shfl_xor(ss, 1); ss += __shfl_xor(ss, 2); ss += __shfl_xor(ss, 4);
    ss += __shfl_xor(ss, 8); ss += __shfl_xor(ss, 16);
    if (r < NN) {
      *(float4*)&atom[(size_t)r*DH + jg*4] = make_float4(v[0],v[1],v[2],v[3]);
      const float inv = 1.f / fmaxf(sqrtf(ss), 1e-12f);
      *(float4*)&normed[(size_t)r*DH + jg*4] = make_float4(v[0]*inv,v[1]*inv,v[2]*inv,v[3]*inv);
    }
  }
}

// ================= per-graph sum + out GEMV =================
__global__ __launch_bounds__(128) void graph_out_kernel(const float* __restrict__ normed, const int* __restrict__ batch,
                                                        const float* __restrict__ Wo, const float* __restrict__ bo,
                                                        float* __restrict__ out){
  const int g = blockIdx.x, t = threadIdx.x;
  int lo, hi;
  { int a=0, bb=NN; while(a<bb){ int m=(a+bb)>>1; if (batch[m] < g) a=m+1; else bb=m; } lo=a; }
  { int a=lo, bb=NN; while(a<bb){ int m=(a+bb)>>1; if (batch[m] < g+1) a=m+1; else bb=m; } hi=a; }
  float s = 0.f;
  for (int n = lo; n < hi; ++n) s += normed[(size_t)n*DH + t];
  float v = s * Wo[t];
  #pragma unroll
  for (int d2 = 1; d2 < 64; d2 <<= 1) v += __shfl_xor(v, d2);
  __shared__ float red[2];
  if ((t & 63) == 0) red[t >> 6] = v;
  __syncthreads();
  if (t == 0) out[g] = red[0] + red[1] + bo[0];
}

extern "C" void kernel_launch(void* const* d_in, const int* in_sizes, int n_in,
                              void* d_out, int out_size, void* d_ws, size_t ws_size,
                              hipStream_t stream)
{
  const float* cf     = (const float*)d_in[1];
  const int*   srt    = (const int*)d_in[2];
  const int*   endi   = (const int*)d_in[3];
  const int*   batch  = (const int*)d_in[5];
  const float* W_init = (const float*)d_in[6];
  const float* b_init = (const float*)d_in[7];
  const float* W_h1   = (const float*)d_in[8];
  const float* b_h1   = (const float*)d_in[9];
  const float* W_mol  = (const float*)d_in[10];
  const float* b_mol  = (const float*)d_in[11];
  const float* W_out  = (const float*)d_in[12];
  const float* b_out  = (const float*)d_in[13];

  float* out  = (float*)d_out;
  float* atom = out + NG;

  char* ws = (char*)d_ws;
  u16*   h      = (u16*)(ws);                    // 256,000,000 B (end-CSR rows, pi cols)
  float* agg    = (float*)(ws + 256000000);      // 25,600,000 B (pi cols)
  float* P      = (float*)(ws + 281600000);      // 25,600,000 B (pi cols)
  float* Q      = (float*)(ws + 307200000);      // 25,600,000 B (pi cols)
  u16*   cfb    = (u16*)(ws + 281600000);        // 40,017,920 B — aliases P+Q (dead during layer0)
  int*   srtE   = (int*)(ws + 332800000);        // 4,000,000 B
  int*   endS   = (int*)(ws + 336800000);        // 4,000,000 B
  int*   rankE  = (int*)(ws + 340800000);        // 4,000,000 B
  int*   listS2 = (int*)(ws + 344800000);        // 4,000,000 B
  int*   offE   = (int*)(ws + 348800000);        // 200,704 B
  int*   offS   = (int*)(ws + 349000704);        // 200,704 B
  int*   curE   = (int*)(ws + 349201408);        // 200,704 B
  int*   curS   = (int*)(ws + 349402112);        // 200,704 B
  u16*   Wb1    = (u16*)(ws + 349602816);        // 32,768 B
  u16*   Wb0    = (u16*)(ws + 349635584);        // 40,960 B
  float* bp0    = (float*)(ws + 349676544);      // 512 B
  float* bp1    = (float*)(ws + 349677056);      // 512 B
  float* hnode  = agg;                           // agg dead after last pq_gemm
  float* normed = (float*)(ws);                  // reuse h region (h dead after fused_last)

  // ---- CSR build (int atomics only)
  hipMemsetAsync(curE, 0, 200704, stream);
  hipMemsetAsync(curS, 0, 200704, stream);
  hist_kernel<<<1024, 256, 0, stream>>>(endi, srt, curE, curS);
  scan2_kernel<<<2, 1024, 0, stream>>>(curE, offE, curS, offS);
  hipMemcpyAsync(curE, offE, (size_t)NN*4, hipMemcpyDeviceToDevice, stream);
  hipMemcpyAsync(curS, offS, (size_t)NN*4, hipMemcpyDeviceToDevice, stream);
  scatter_kernel<<<1024, 256, 0, stream>>>(endi, srt, curE, curS, rankE, srtE, listS2, endS);
  convertW_kernel<<<80, 256, 0, stream>>>(W_h1, W_init, b_init, b_h1, Wb1, Wb0, bp0, bp1);

  // ---- layer 0: chunked cvt + MFMA gemm (cfb aliases P/Q)
  for (int k = 0; k < 8; ++k){
    const int lo = k*CH;
    const int hi = (lo + CH < NE) ? lo + CH : NE;
    const int nrow = hi - lo;
    cvt_cf<<<(nrow*20 + 255)/256, 256, 0, stream>>>(cf, cfb, lo, hi);
    layer0_gemm<<<(nrow + 127)/128, 256, 0, stream>>>(cfb, Wb0, bp0, rankE, h, lo, hi);
  }
  aggE_kernel<<<NN/4, 256, 0, stream>>>(h, offE, agg);

  // ---- layers 1..2: tiny P/Q GEMMs + fused sequential update producing next agg
  for (int l = 0; l < 2; ++l){
    pq_gemm<<<(2*NN + 127)/128, 256, 0, stream>>>(agg, h, rankE, Wb1, bp1, P, Q);
    fused_mid<<<NN/4, 256, 0, stream>>>(h, P, Q, srtE, offE, agg);
  }
  // ---- layer 3: P/Q then direct hnode accumulation (no h write, no separate gather)
  pq_gemm<<<(2*NN + 127)/128, 256, 0, stream>>>(agg, h, rankE, Wb1, bp1, P, Q);
  fused_last<<<NN/4, 256, 0, stream>>>(h, P, Q, endS, listS2, offS, hnode);

  // ---- node MLP + normalize, per-graph sum + out
  node_kernel<<<(NN + 31)/32, 256, 0, stream>>>(hnode, W_mol, b_mol, atom, normed);
  graph_out_kernel<<<NG, 128, 0, stream>>>(normed, batch, W_out, b_out, out);
}

// Round 8
// 1235.899 us; speedup vs baseline: 1.1769x; 1.1769x over previous
//
#include <hip/hip_runtime.h>

#define NN 50000
#define NE 1000000
#define NG 1000
#define KE 147
#define DH 128

using u16 = unsigned short;
typedef __attribute__((ext_vector_type(8))) short bf16x8;
typedef __attribute__((ext_vector_type(4))) float f32x4;

__device__ __forceinline__ float lrelu(float v){ return fmaxf(v, 0.01f*v); }
__device__ __forceinline__ float bf2f(u16 u){ unsigned int x = ((unsigned int)u)<<16; float f; __builtin_memcpy(&f,&x,4); return f; }
__device__ __forceinline__ u16 f2bf(float f){ unsigned int x; __builtin_memcpy(&x,&f,4); x += 0x7fffu + ((x>>16)&1u); return (u16)(x>>16); }
__device__ __forceinline__ float bflo(unsigned w){ unsigned x = w<<16; float f; __builtin_memcpy(&f,&x,4); return f; }
__device__ __forceinline__ float bfhi(unsigned w){ unsigned x = w & 0xffff0000u; float f; __builtin_memcpy(&f,&x,4); return f; }
__device__ __forceinline__ unsigned pk2(float lo, float hi){ return ((unsigned)f2bf(hi)<<16) | (unsigned)f2bf(lo); }
// column permutation: memory position p holds logical column cpi(p)
__device__ __host__ __forceinline__ int cpi(int p){ return (p & 64) | ((p & 3) << 4) | ((p & 63) >> 2); }

// ================= CSR build =================
__global__ __launch_bounds__(256) void hist_kernel(const int* __restrict__ endi, const int* __restrict__ srt,
                                                   int* __restrict__ cntE, int* __restrict__ cntS){
  for (int i = blockIdx.x*256 + threadIdx.x; i < NE; i += gridDim.x*256){
    atomicAdd(&cntE[endi[i]], 1);
    atomicAdd(&cntS[srt[i]], 1);
  }
}

__global__ __launch_bounds__(1024) void scan2_kernel(const int* __restrict__ cntE, int* __restrict__ offE,
                                                     const int* __restrict__ cntS, int* __restrict__ offS){
  const int* deg = blockIdx.x ? cntS : cntE;
  int* off = blockIdx.x ? offS : offE;
  __shared__ int wsum[17];
  const int t = threadIdx.x, lane = t & 63, wv = t >> 6;
  int carry = 0;
  for (int base = 0; base < 50176; base += 1024){
    const int i = base + t;
    int v = (i < NN) ? deg[i] : 0;
    int s = v;
    #pragma unroll
    for (int d = 1; d < 64; d <<= 1){
      int x = __shfl_up(s, d);
      if (lane >= d) s += x;
    }
    if (lane == 63) wsum[wv] = s;
    __syncthreads();
    if (t == 0){
      int run = 0;
      #pragma unroll
      for (int k = 0; k < 16; ++k){ int x = wsum[k]; wsum[k] = run; run += x; }
      wsum[16] = run;
    }
    __syncthreads();
    if (i <= NN) off[i] = carry + wsum[wv] + s - v;
    carry += wsum[16];
    __syncthreads();
  }
}

// scatter: rankE (edge->permuted row), srtE (per row), listS2 (srt-CSR -> permuted row), endS
__global__ __launch_bounds__(256) void scatter_kernel(const int* __restrict__ endi, const int* __restrict__ srt,
                                                      int* __restrict__ curE, int* __restrict__ curS,
                                                      int* __restrict__ rankE, int* __restrict__ srtE,
                                                      int* __restrict__ listS2, int* __restrict__ endS){
  for (int i = blockIdx.x*256 + threadIdx.x; i < NE; i += gridDim.x*256){
    const int e = endi[i], s = srt[i];
    int p = atomicAdd(&curE[e], 1);
    rankE[i] = p; srtE[p] = s;
    int q = atomicAdd(&curS[s], 1);
    listS2[q] = p; endS[q] = e;
  }
}

// Wb0: natural layout padded K=160. Wb1: K permuted by cpi. bp0/bp1: biases permuted by cpi.
__global__ __launch_bounds__(256) void convertW_kernel(const float* __restrict__ W1, const float* __restrict__ W0,
                                                       const float* __restrict__ b0, const float* __restrict__ b1,
                                                       u16* __restrict__ Wb1, u16* __restrict__ Wb0,
                                                       float* __restrict__ bp0, float* __restrict__ bp1){
  int i = blockIdx.x*256 + threadIdx.x;
  if (i < 128*128){
    int j = i >> 7, k = i & 127;
    Wb1[i] = f2bf(W1[j*DH + cpi(k)]);
  }
  if (i < 128*160){
    int j = i/160, k = i - j*160;
    Wb0[i] = (k < KE) ? f2bf(W0[j*KE + k]) : (u16)0;
  }
  if (i < 128){ bp0[i] = b0[cpi(i)]; bp1[i] = b1[cpi(i)]; }
}

// ================= layer 0: h'[rankE[e]] = lrelu(cf[e] @ W0^T + b) =================
// LDS bf16 tile [128][168]; staging via flat float4 global loads (tile base is 16B-aligned:
// 128*147*4 = 75264 ≡ 0 mod 16) + wrap-increment (r,c) scalar ds writes.
__global__ __launch_bounds__(256) void layer0_mfma(const float* __restrict__ cf, const u16* __restrict__ Wb0,
                                                   const float* __restrict__ bp0, const int* __restrict__ rankE,
                                                   u16* __restrict__ h){
  __shared__ __align__(16) u16 As[128*168];   // 43,008 B
  const int t = threadIdx.x, lane = t & 63, wv = t >> 6;
  const int wr = wv >> 1, wc = wv & 1;
  const int e0 = blockIdx.x * 128;
  const int q = lane & 15, kg8 = (lane >> 4)*8;

  bf16x8 bfrag[5][4];
  #pragma unroll
  for (int fc = 0; fc < 4; ++fc)
    #pragma unroll
    for (int ks = 0; ks < 5; ++ks)
      bfrag[ks][fc] = *(const bf16x8*)&Wb0[(size_t)(wc*64 + fc*16 + q)*160 + ks*32 + kg8];

  const bool full = (e0 + 128 <= NE);
  int nf4 = 4704;                              // 128*147/4
  if (!full){
    // tail block (64 rows): zero whole tile first
    unsigned* a32 = (unsigned*)As;
    for (int i = t; i < 128*168/2; i += 256) a32[i] = 0;
    __syncthreads();
    nf4 = 2352;                                // 64*147/4
  }
  {
    const float4* src = (const float4*)(cf + (size_t)e0*KE);
    #pragma unroll
    for (int k = 0; k < 19; ++k){
      const int i4 = t + k*256;
      if (i4 < nf4){
        float4 v = src[i4];
        const int g = i4*4;
        int r = (unsigned)g / 147u;
        int c = g - r*147;
        u16 w0 = f2bf(v.x), w1 = f2bf(v.y), w2 = f2bf(v.z), w3 = f2bf(v.w);
        As[r*168 + c] = w0; if (++c == 147){ c = 0; ++r; }
        As[r*168 + c] = w1; if (++c == 147){ c = 0; ++r; }
        As[r*168 + c] = w2; if (++c == 147){ c = 0; ++r; }
        As[r*168 + c] = w3;
      }
    }
  }
  // zero pad cols 147..159
  for (int idx = t; idx < 2048; idx += 256){
    const int r = idx >> 4, c = idx & 15;
    if (c < 13) As[r*168 + 147 + c] = 0;
  }
  __syncthreads();

  f32x4 acc[4][4];
  #pragma unroll
  for (int fr = 0; fr < 4; ++fr)
    #pragma unroll
    for (int fc = 0; fc < 4; ++fc){ acc[fr][fc][0]=0.f; acc[fr][fc][1]=0.f; acc[fr][fc][2]=0.f; acc[fr][fc][3]=0.f; }
  #pragma unroll
  for (int ks = 0; ks < 5; ++ks){
    bf16x8 a[4];
    #pragma unroll
    for (int fr = 0; fr < 4; ++fr)
      a[fr] = *(const bf16x8*)&As[(wr*64 + fr*16 + q)*168 + ks*32 + kg8];
    #pragma unroll
    for (int fr = 0; fr < 4; ++fr)
      #pragma unroll
      for (int fc = 0; fc < 4; ++fc)
        acc[fr][fc] = __builtin_amdgcn_mfma_f32_16x16x32_bf16(a[fr], bfrag[ks][fc], acc[fr][fc], 0, 0, 0);
  }

  const float4 bb = *(const float4*)&bp0[wc*64 + q*4];
  #pragma unroll
  for (int fr = 0; fr < 4; ++fr){
    #pragma unroll
    for (int r = 0; r < 4; ++r){
      const int ee = e0 + wr*64 + fr*16 + (lane>>4)*4 + r;
      if (ee < NE){
        const int row = rankE[ee];
        ushort4 o;
        o.x = f2bf(lrelu(acc[fr][0][r] + bb.x));
        o.y = f2bf(lrelu(acc[fr][1][r] + bb.y));
        o.z = f2bf(lrelu(acc[fr][2][r] + bb.z));
        o.w = f2bf(lrelu(acc[fr][3][r] + bb.w));
        *(ushort4*)&h[(size_t)row*DH + wc*64 + q*4] = o;
      }
    }
  }
}

// ================= agg[n] = sum of h' rows [offE[n], offE[n+1]) — 4-way ILP =================
__global__ __launch_bounds__(256) void aggE_kernel(const u16* __restrict__ h, const int* __restrict__ off,
                                                   float* __restrict__ agg){
  const int t = threadIdx.x, lane = t & 63, wv = t >> 6;
  const int n = blockIdx.x*4 + wv;
  if (n >= NN) return;
  const int lo = off[n], hi = off[n+1];
  const int c8 = (lane & 15)*8, sub = lane >> 4;
  float a0=0,a1=0,a2=0,a3=0,a4=0,a5=0,a6=0,a7=0;
  for (int i = lo + sub; i < hi; i += 4){
    uint4 hv = *(const uint4*)&h[(size_t)i*DH + c8];
    a0 += bflo(hv.x); a1 += bfhi(hv.x); a2 += bflo(hv.y); a3 += bfhi(hv.y);
    a4 += bflo(hv.z); a5 += bfhi(hv.z); a6 += bflo(hv.w); a7 += bfhi(hv.w);
  }
  a0 += __shfl_xor(a0,16); a1 += __shfl_xor(a1,16); a2 += __shfl_xor(a2,16); a3 += __shfl_xor(a3,16);
  a4 += __shfl_xor(a4,16); a5 += __shfl_xor(a5,16); a6 += __shfl_xor(a6,16); a7 += __shfl_xor(a7,16);
  a0 += __shfl_xor(a0,32); a1 += __shfl_xor(a1,32); a2 += __shfl_xor(a2,32); a3 += __shfl_xor(a3,32);
  a4 += __shfl_xor(a4,32); a5 += __shfl_xor(a5,32); a6 += __shfl_xor(a6,32); a7 += __shfl_xor(a7,32);
  if (sub == 0){
    *(float4*)&agg[(size_t)n*DH + c8]     = make_float4(a0,a1,a2,a3);
    *(float4*)&agg[(size_t)n*DH + c8 + 4] = make_float4(a4,a5,a6,a7);
  }
}

// ================= P/Q GEMM: P = agg@W^T + b ; Q = h'[rankE[0:N]]@W^T  (pi space in/out) =====
__global__ __launch_bounds__(256) void pq_gemm(const float* __restrict__ agg, const u16* __restrict__ h,
                                               const int* __restrict__ rankE, const u16* __restrict__ Wb1,
                                               const float* __restrict__ bp1, float* __restrict__ P,
                                               float* __restrict__ Q){
  __shared__ u16 Alds[128][136];
  const int t = threadIdx.x, lane = t & 63, wv = t >> 6;
  const int wr = wv >> 1, wc = wv & 1;
  const int r0 = blockIdx.x * 128;
  const int q = lane & 15, kg8 = (lane >> 4)*8;

  bf16x8 bfrag[4][4];
  #pragma unroll
  for (int fc = 0; fc < 4; ++fc)
    #pragma unroll
    for (int ks = 0; ks < 4; ++ks)
      bfrag[ks][fc] = *(const bf16x8*)&Wb1[(size_t)(wc*64 + fc*16 + q)*128 + ks*32 + kg8];

  {
    const int rt = t >> 1, half = t & 1;
    const int gr = r0 + rt;
    u16* dst = &Alds[rt][half*64];
    if (gr < NN){
      const float4* src = (const float4*)&agg[(size_t)gr*DH + half*64];
      #pragma unroll
      for (int p = 0; p < 16; ++p){
        float4 x = src[p];
        ushort4 o; o.x=f2bf(x.x); o.y=f2bf(x.y); o.z=f2bf(x.z); o.w=f2bf(x.w);
        *(ushort4*)&dst[p*4] = o;
      }
    } else if (gr < 2*NN){
      const int row = rankE[gr - NN];
      const ushort4* src = (const ushort4*)&h[(size_t)row*DH + half*64];
      #pragma unroll
      for (int p = 0; p < 16; ++p) *(ushort4*)&dst[p*4] = src[p];
    } else {
      ushort4 z; z.x=0; z.y=0; z.z=0; z.w=0;
      #pragma unroll
      for (int p = 0; p < 16; ++p) *(ushort4*)&dst[p*4] = z;
    }
  }
  __syncthreads();

  f32x4 acc[4][4];
  #pragma unroll
  for (int fr = 0; fr < 4; ++fr)
    #pragma unroll
    for (int fc = 0; fc < 4; ++fc){ acc[fr][fc][0]=0.f; acc[fr][fc][1]=0.f; acc[fr][fc][2]=0.f; acc[fr][fc][3]=0.f; }
  #pragma unroll
  for (int ks = 0; ks < 4; ++ks){
    bf16x8 a[4];
    #pragma unroll
    for (int fr = 0; fr < 4; ++fr)
      a[fr] = *(const bf16x8*)&Alds[wr*64 + fr*16 + q][ks*32 + kg8];
    #pragma unroll
    for (int fr = 0; fr < 4; ++fr)
      #pragma unroll
      for (int fc = 0; fc < 4; ++fc)
        acc[fr][fc] = __builtin_amdgcn_mfma_f32_16x16x32_bf16(a[fr], bfrag[ks][fc], acc[fr][fc], 0, 0, 0);
  }

  const float4 bb = *(const float4*)&bp1[wc*64 + q*4];
  #pragma unroll
  for (int fr = 0; fr < 4; ++fr){
    #pragma unroll
    for (int r = 0; r < 4; ++r){
      const int grow = r0 + wr*64 + fr*16 + (lane>>4)*4 + r;
      if (grow < NN){
        float4 val = make_float4(acc[fr][0][r] + bb.x, acc[fr][1][r] + bb.y,
                                 acc[fr][2][r] + bb.z, acc[fr][3][r] + bb.w);
        *(float4*)&P[(size_t)grow*DH + wc*64 + q*4] = val;
      } else if (grow < 2*NN){
        float4 val = make_float4(acc[fr][0][r], acc[fr][1][r], acc[fr][2][r], acc[fr][3][r]);
        *(float4*)&Q[(size_t)(grow-NN)*DH + wc*64 + q*4] = val;
      }
    }
  }
}

// ===== middle layers: h'[i] = lrelu(h'[i] + P[srtE[i]] - Q[n]); agg[n]=sum — 4-way ILP =====
__global__ __launch_bounds__(256) void fused_mid(u16* __restrict__ h, const float* __restrict__ P,
                                                 const float* __restrict__ Q, const int* __restrict__ srtE,
                                                 const int* __restrict__ off, float* __restrict__ agg){
  const int t = threadIdx.x, lane = t & 63, wv = t >> 6;
  const int n = blockIdx.x*4 + wv;
  if (n >= NN) return;
  const int lo = off[n], hi = off[n+1];
  const int c8 = (lane & 15)*8, sub = lane >> 4;
  const float4 q0 = *(const float4*)&Q[(size_t)n*DH + c8];
  const float4 q1 = *(const float4*)&Q[(size_t)n*DH + c8 + 4];
  float a0=0,a1=0,a2=0,a3=0,a4=0,a5=0,a6=0,a7=0;
  for (int i = lo + sub; i < hi; i += 4){
    const int s = srtE[i];
    uint4 hv = *(const uint4*)&h[(size_t)i*DH + c8];
    float4 p0 = *(const float4*)&P[(size_t)s*DH + c8];
    float4 p1 = *(const float4*)&P[(size_t)s*DH + c8 + 4];
    float v0 = lrelu(bflo(hv.x) + p0.x - q0.x);
    float v1 = lrelu(bfhi(hv.x) + p0.y - q0.y);
    float v2 = lrelu(bflo(hv.y) + p0.z - q0.z);
    float v3 = lrelu(bfhi(hv.y) + p0.w - q0.w);
    float v4 = lrelu(bflo(hv.z) + p1.x - q1.x);
    float v5 = lrelu(bfhi(hv.z) + p1.y - q1.y);
    float v6 = lrelu(bflo(hv.w) + p1.z - q1.z);
    float v7 = lrelu(bfhi(hv.w) + p1.w - q1.w);
    uint4 o;
    o.x = pk2(v0, v1); o.y = pk2(v2, v3); o.z = pk2(v4, v5); o.w = pk2(v6, v7);
    *(uint4*)&h[(size_t)i*DH + c8] = o;
    a0+=v0; a1+=v1; a2+=v2; a3+=v3; a4+=v4; a5+=v5; a6+=v6; a7+=v7;
  }
  a0 += __shfl_xor(a0,16); a1 += __shfl_xor(a1,16); a2 += __shfl_xor(a2,16); a3 += __shfl_xor(a3,16);
  a4 += __shfl_xor(a4,16); a5 += __shfl_xor(a5,16); a6 += __shfl_xor(a6,16); a7 += __shfl_xor(a7,16);
  a0 += __shfl_xor(a0,32); a1 += __shfl_xor(a1,32); a2 += __shfl_xor(a2,32); a3 += __shfl_xor(a3,32);
  a4 += __shfl_xor(a4,32); a5 += __shfl_xor(a5,32); a6 += __shfl_xor(a6,32); a7 += __shfl_xor(a7,32);
  if (sub == 0){
    *(float4*)&agg[(size_t)n*DH + c8]     = make_float4(a0,a1,a2,a3);
    *(float4*)&agg[(size_t)n*DH + c8 + 4] = make_float4(a4,a5,a6,a7);
  }
}

// ===== last layer: hnode[s] = sum over srt-CSR of lrelu(h'[listS2[i]] + P[s] - Q[endS[i]]) — 4-way =====
__global__ __launch_bounds__(256) void fused_last(const u16* __restrict__ h, const float* __restrict__ P,
                                                  const float* __restrict__ Q, const int* __restrict__ endS,
                                                  const int* __restrict__ listS2, const int* __restrict__ off,
                                                  float* __restrict__ hnode){
  const int t = threadIdx.x, lane = t & 63, wv = t >> 6;
  const int s = blockIdx.x*4 + wv;
  if (s >= NN) return;
  const int lo = off[s], hi = off[s+1];
  const int c8 = (lane & 15)*8, sub = lane >> 4;
  const float4 p0 = *(const float4*)&P[(size_t)s*DH + c8];
  const float4 p1 = *(const float4*)&P[(size_t)s*DH + c8 + 4];
  float a0=0,a1=0,a2=0,a3=0,a4=0,a5=0,a6=0,a7=0;
  for (int i = lo + sub; i < hi; i += 4){
    const int row = listS2[i];
    const int d = endS[i];
    uint4 hv = *(const uint4*)&h[(size_t)row*DH + c8];
    float4 q0 = *(const float4*)&Q[(size_t)d*DH + c8];
    float4 q1 = *(const float4*)&Q[(size_t)d*DH + c8 + 4];
    a0 += lrelu(bflo(hv.x) + p0.x - q0.x);
    a1 += lrelu(bfhi(hv.x) + p0.y - q0.y);
    a2 += lrelu(bflo(hv.y) + p0.z - q0.z);
    a3 += lrelu(bfhi(hv.y) + p0.w - q0.w);
    a4 += lrelu(bflo(hv.z) + p1.x - q1.x);
    a5 += lrelu(bfhi(hv.z) + p1.y - q1.y);
    a6 += lrelu(bflo(hv.w) + p1.z - q1.z);
    a7 += lrelu(bfhi(hv.w) + p1.w - q1.w);
  }
  a0 += __shfl_xor(a0,16); a1 += __shfl_xor(a1,16); a2 += __shfl_xor(a2,16); a3 += __shfl_xor(a3,16);
  a4 += __shfl_xor(a4,16); a5 += __shfl_xor(a5,16); a6 += __shfl_xor(a6,16); a7 += __shfl_xor(a7,16);
  a0 += __shfl_xor(a0,32); a1 += __shfl_xor(a1,32); a2 += __shfl_xor(a2,32); a3 += __shfl_xor(a3,32);
  a4 += __shfl_xor(a4,32); a5 += __shfl_xor(a5,32); a6 += __shfl_xor(a6,32); a7 += __shfl_xor(a7,32);
  if (sub == 0){
    *(float4*)&hnode[(size_t)s*DH + c8]     = make_float4(a0,a1,a2,a3);
    *(float4*)&hnode[(size_t)s*DH + c8 + 4] = make_float4(a4,a5,a6,a7);
  }
}

// ================= nodes: atom = lrelu(hnode @ Wmol^T + b); normed = atom/||atom|| =================
// hnode columns are pi-permuted; permute Wmol's K during staging. Outputs canonical.
__global__ __launch_bounds__(256) void node_kernel(
    const float* __restrict__ hn, const float* __restrict__ W,
    const float* __restrict__ b, float* __restrict__ atom, float* __restrict__ normed)
{
  __shared__ float Wt[64*132];
  __shared__ float ms[32*DH];
  const int t = threadIdx.x;
  const int r0 = blockIdx.x * 32;
  const int jg = t & 31, eg = t >> 5;
  for (int idx = t; idx < 32*DH; idx += 256) {
    const int r = r0 + (idx >> 7);
    ms[idx] = (r < NN) ? hn[(size_t)r*DH + (idx & 127)] : 0.f;
  }
  float acc[4][4] = {};
  for (int c = 0; c < 2; ++c) {
    __syncthreads();
    for (int idx = t; idx < 128*64; idx += 256) {
      const int j = idx >> 6, kl = idx & 63;
      Wt[kl*132 + j] = W[j*DH + c*64 + ((kl&3)*16 + (kl>>2))];   // pi64 on K
    }
    __syncthreads();
    #pragma unroll 4
    for (int kl = 0; kl < 64; ++kl) {
      const float4 w = *(const float4*)&Wt[kl*132 + jg*4];
      const int kg = c*64 + kl;
      #pragma unroll
      for (int i = 0; i < 4; ++i) {
        const float mv = ms[(eg*4+i)*DH + kg];
        acc[i][0] += mv*w.x; acc[i][1] += mv*w.y; acc[i][2] += mv*w.z; acc[i][3] += mv*w.w;
      }
    }
  }
  float bj[4];
  #pragma unroll
  for (int c2 = 0; c2 < 4; ++c2) bj[c2] = b[jg*4 + c2];
  #pragma unroll
  for (int i = 0; i < 4; ++i) {
    const int r = r0 + eg*4 + i;
    float v[4]; float ss = 0.f;
    #pragma unroll
    for (int c2 = 0; c2 < 4; ++c2) { v[c2] = lrelu(acc[i][c2] + bj[c2]); ss += v[c2]*v[c2]; }
    ss += __shfl_xor(ss, 1); ss += __shfl_xor(ss, 2); ss += __shfl_xor(ss, 4);
    ss += __shfl_xor(ss, 8); ss += __shfl_xor(ss, 16);
    if (r < NN) {
      *(float4*)&atom[(size_t)r*DH + jg*4] = make_float4(v[0],v[1],v[2],v[3]);
      const float inv = 1.f / fmaxf(sqrtf(ss), 1e-12f);
      *(float4*)&normed[(size_t)r*DH + jg*4] = make_float4(v[0]*inv,v[1]*inv,v[2]*inv,v[3]*inv);
    }
  }
}

// ================= per-graph sum + out GEMV =================
__global__ __launch_bounds__(128) void graph_out_kernel(const float* __restrict__ normed, const int* __restrict__ batch,
                                                        const float* __restrict__ Wo, const float* __restrict__ bo,
                                                        float* __restrict__ out){
  const int g = blockIdx.x, t = threadIdx.x;
  int lo, hi;
  { int a=0, bb=NN; while(a<bb){ int m=(a+bb)>>1; if (batch[m] < g) a=m+1; else bb=m; } lo=a; }
  { int a=lo, bb=NN; while(a<bb){ int m=(a+bb)>>1; if (batch[m] < g+1) a=m+1; else bb=m; } hi=a; }
  float s = 0.f;
  for (int n = lo; n < hi; ++n) s += normed[(size_t)n*DH + t];
  float v = s * Wo[t];
  #pragma unroll
  for (int d2 = 1; d2 < 64; d2 <<= 1) v += __shfl_xor(v, d2);
  __shared__ float red[2];
  if ((t & 63) == 0) red[t >> 6] = v;
  __syncthreads();
  if (t == 0) out[g] = red[0] + red[1] + bo[0];
}

extern "C" void kernel_launch(void* const* d_in, const int* in_sizes, int n_in,
                              void* d_out, int out_size, void* d_ws, size_t ws_size,
                              hipStream_t stream)
{
  const float* cf     = (const float*)d_in[1];
  const int*   srt    = (const int*)d_in[2];
  const int*   endi   = (const int*)d_in[3];
  const int*   batch  = (const int*)d_in[5];
  const float* W_init = (const float*)d_in[6];
  const float* b_init = (const float*)d_in[7];
  const float* W_h1   = (const float*)d_in[8];
  const float* b_h1   = (const float*)d_in[9];
  const float* W_mol  = (const float*)d_in[10];
  const float* b_mol  = (const float*)d_in[11];
  const float* W_out  = (const float*)d_in[12];
  const float* b_out  = (const float*)d_in[13];

  float* out  = (float*)d_out;
  float* atom = out + NG;

  char* ws = (char*)d_ws;
  u16*   h      = (u16*)(ws);                    // 256,000,000 B (end-CSR rows, pi cols)
  float* agg    = (float*)(ws + 256000000);      // 25,600,000 B (pi cols)
  float* P      = (float*)(ws + 281600000);      // 25,600,000 B (pi cols)
  float* Q      = (float*)(ws + 307200000);      // 25,600,000 B (pi cols)
  int*   srtE   = (int*)(ws + 332800000);        // 4,000,000 B
  int*   endS   = (int*)(ws + 336800000);        // 4,000,000 B
  int*   rankE  = (int*)(ws + 340800000);        // 4,000,000 B
  int*   listS2 = (int*)(ws + 344800000);        // 4,000,000 B
  int*   offE   = (int*)(ws + 348800000);        // 200,704 B
  int*   offS   = (int*)(ws + 349000704);        // 200,704 B
  int*   curE   = (int*)(ws + 349201408);        // 200,704 B
  int*   curS   = (int*)(ws + 349402112);        // 200,704 B
  u16*   Wb1    = (u16*)(ws + 349602816);        // 32,768 B
  u16*   Wb0    = (u16*)(ws + 349635584);        // 40,960 B
  float* bp0    = (float*)(ws + 349676544);      // 512 B
  float* bp1    = (float*)(ws + 349677056);      // 512 B
  float* hnode  = agg;                           // agg dead after last pq_gemm
  float* normed = (float*)(ws);                  // reuse h region (h dead after fused_last)

  // ---- CSR build (int atomics only)
  hipMemsetAsync(curE, 0, 200704, stream);
  hipMemsetAsync(curS, 0, 200704, stream);
  hist_kernel<<<1024, 256, 0, stream>>>(endi, srt, curE, curS);
  scan2_kernel<<<2, 1024, 0, stream>>>(curE, offE, curS, offS);
  hipMemcpyAsync(curE, offE, (size_t)NN*4, hipMemcpyDeviceToDevice, stream);
  hipMemcpyAsync(curS, offS, (size_t)NN*4, hipMemcpyDeviceToDevice, stream);
  scatter_kernel<<<1024, 256, 0, stream>>>(endi, srt, curE, curS, rankE, srtE, listS2, endS);
  convertW_kernel<<<80, 256, 0, stream>>>(W_h1, W_init, b_init, b_h1, Wb1, Wb0, bp0, bp1);

  // ---- layer 0 (LDS-staged MFMA; writes h in end-CSR row order, pi col order)
  layer0_mfma<<<(NE + 127)/128, 256, 0, stream>>>(cf, Wb0, bp0, rankE, h);
  aggE_kernel<<<NN/4, 256, 0, stream>>>(h, offE, agg);

  // ---- layers 1..2: tiny P/Q GEMMs + fused sequential update producing next agg
  for (int l = 0; l < 2; ++l){
    pq_gemm<<<(2*NN + 127)/128, 256, 0, stream>>>(agg, h, rankE, Wb1, bp1, P, Q);
    fused_mid<<<NN/4, 256, 0, stream>>>(h, P, Q, srtE, offE, agg);
  }
  // ---- layer 3: P/Q then direct hnode accumulation (no h write, no separate gather)
  pq_gemm<<<(2*NN + 127)/128, 256, 0, stream>>>(agg, h, rankE, Wb1, bp1, P, Q);
  fused_last<<<NN/4, 256, 0, stream>>>(h, P, Q, endS, listS2, offS, hnode);

  // ---- node MLP + normalize, per-graph sum + out
  node_kernel<<<(NN + 31)/32, 256, 0, stream>>>(hnode, W_mol, b_mol, atom, normed);
  graph_out_kernel<<<NG, 128, 0, stream>>>(normed, batch, W_out, b_out, out);
}

// Round 11
// 1120.508 us; speedup vs baseline: 1.2981x; 1.1030x over previous
//
#include <hip/hip_runtime.h>

#define NN 50000
#define NE 1000000
#define NG 1000
#define KE 147
#define DH 128

using u16 = unsigned short;
typedef __attribute__((ext_vector_type(8))) short bf16x8;
typedef __attribute__((ext_vector_type(4))) float f32x4;

__device__ __forceinline__ float lrelu(float v){ return fmaxf(v, 0.01f*v); }
__device__ __forceinline__ float bf2f(u16 u){ unsigned int x = ((unsigned int)u)<<16; float f; __builtin_memcpy(&f,&x,4); return f; }
__device__ __forceinline__ u16 f2bf(float f){ unsigned int x; __builtin_memcpy(&x,&f,4); x += 0x7fffu + ((x>>16)&1u); return (u16)(x>>16); }
__device__ __forceinline__ float bflo(unsigned w){ unsigned x = w<<16; float f; __builtin_memcpy(&f,&x,4); return f; }
__device__ __forceinline__ float bfhi(unsigned w){ unsigned x = w & 0xffff0000u; float f; __builtin_memcpy(&f,&x,4); return f; }
__device__ __forceinline__ unsigned pk2(float lo, float hi){ return ((unsigned)f2bf(hi)<<16) | (unsigned)f2bf(lo); }
// column permutation: memory position p holds logical column cpi(p)
__device__ __host__ __forceinline__ int cpi(int p){ return (p & 64) | ((p & 3) << 4) | ((p & 63) >> 2); }

// ================= CSR build =================
__global__ __launch_bounds__(256) void hist_kernel(const int* __restrict__ endi, const int* __restrict__ srt,
                                                   int* __restrict__ cntE, int* __restrict__ cntS){
  for (int i = blockIdx.x*256 + threadIdx.x; i < NE; i += gridDim.x*256){
    atomicAdd(&cntE[endi[i]], 1);
    atomicAdd(&cntS[srt[i]], 1);
  }
}

__global__ __launch_bounds__(1024) void scan2_kernel(const int* __restrict__ cntE, int* __restrict__ offE,
                                                     const int* __restrict__ cntS, int* __restrict__ offS){
  const int* deg = blockIdx.x ? cntS : cntE;
  int* off = blockIdx.x ? offS : offE;
  __shared__ int wsum[17];
  const int t = threadIdx.x, lane = t & 63, wv = t >> 6;
  int carry = 0;
  for (int base = 0; base < 50176; base += 1024){
    const int i = base + t;
    int v = (i < NN) ? deg[i] : 0;
    int s = v;
    #pragma unroll
    for (int d = 1; d < 64; d <<= 1){
      int x = __shfl_up(s, d);
      if (lane >= d) s += x;
    }
    if (lane == 63) wsum[wv] = s;
    __syncthreads();
    if (t == 0){
      int run = 0;
      #pragma unroll
      for (int k = 0; k < 16; ++k){ int x = wsum[k]; wsum[k] = run; run += x; }
      wsum[16] = run;
    }
    __syncthreads();
    if (i <= NN) off[i] = carry + wsum[wv] + s - v;
    carry += wsum[16];
    __syncthreads();
  }
}

// scatter: rankE (edge->permuted row), srtE (per row), listS2 (srt-CSR -> permuted row), endS
__global__ __launch_bounds__(256) void scatter_kernel(const int* __restrict__ endi, const int* __restrict__ srt,
                                                      int* __restrict__ curE, int* __restrict__ curS,
                                                      int* __restrict__ rankE, int* __restrict__ srtE,
                                                      int* __restrict__ listS2, int* __restrict__ endS){
  for (int i = blockIdx.x*256 + threadIdx.x; i < NE; i += gridDim.x*256){
    const int e = endi[i], s = srt[i];
    int p = atomicAdd(&curE[e], 1);
    rankE[i] = p; srtE[p] = s;
    int q = atomicAdd(&curS[s], 1);
    listS2[q] = p; endS[q] = e;
  }
}

// Wb0: natural layout padded K=160. Wb1: K permuted by cpi. bp0/bp1: biases permuted by cpi.
__global__ __launch_bounds__(256) void convertW_kernel(const float* __restrict__ W1, const float* __restrict__ W0,
                                                       const float* __restrict__ b0, const float* __restrict__ b1,
                                                       u16* __restrict__ Wb1, u16* __restrict__ Wb0,
                                                       float* __restrict__ bp0, float* __restrict__ bp1){
  int i = blockIdx.x*256 + threadIdx.x;
  if (i < 128*128){
    int j = i >> 7, k = i & 127;
    Wb1[i] = f2bf(W1[j*DH + cpi(k)]);
  }
  if (i < 128*160){
    int j = i/160, k = i - j*160;
    Wb0[i] = (k < KE) ? f2bf(W0[j*KE + k]) : (u16)0;
  }
  if (i < 128){ bp0[i] = b0[cpi(i)]; bp1[i] = b1[cpi(i)]; }
}

// ================= layer 0: h'[rankE[e]] = lrelu(cf[e] @ W0^T + b) =================
// 64-row tile (21.5 KB LDS -> 7 blocks/CU by LDS), NE % 64 == 0 so no tail guards.
__global__ __launch_bounds__(256) void layer0_mfma(const float* __restrict__ cf, const u16* __restrict__ Wb0,
                                                   const float* __restrict__ bp0, const int* __restrict__ rankE,
                                                   u16* __restrict__ h){
  __shared__ __align__(16) u16 As[64*168];    // 21,504 B
  const int t = threadIdx.x, lane = t & 63, wv = t >> 6;
  const int wr = wv >> 1, wc = wv & 1;
  const int e0 = blockIdx.x * 64;
  const int q = lane & 15, kg8 = (lane >> 4)*8;

  bf16x8 bfrag[5][4];
  #pragma unroll
  for (int fc = 0; fc < 4; ++fc)
    #pragma unroll
    for (int ks = 0; ks < 5; ++ks)
      bfrag[ks][fc] = *(const bf16x8*)&Wb0[(size_t)(wc*64 + fc*16 + q)*160 + ks*32 + kg8];

  {
    const float4* src = (const float4*)(cf + (size_t)e0*KE);   // 64*147*4 B, base 16B-aligned
    #pragma unroll
    for (int k = 0; k < 10; ++k){
      const int i4 = t + k*256;
      if (i4 < 2352){                         // 64*147/4
        float4 v = src[i4];
        const int g = i4*4;
        int r = (unsigned)g / 147u;
        int c = g - r*147;
        u16 w0 = f2bf(v.x), w1 = f2bf(v.y), w2 = f2bf(v.z), w3 = f2bf(v.w);
        As[r*168 + c] = w0; if (++c == 147){ c = 0; ++r; }
        As[r*168 + c] = w1; if (++c == 147){ c = 0; ++r; }
        As[r*168 + c] = w2; if (++c == 147){ c = 0; ++r; }
        As[r*168 + c] = w3;
      }
    }
  }
  // zero pad cols 147..159 (ks=4 reads them; keep zeroed)
  for (int idx = t; idx < 64*16; idx += 256){
    const int r = idx >> 4, c = idx & 15;
    if (c < 13) As[r*168 + 147 + c] = 0;
  }
  __syncthreads();

  f32x4 acc[2][4];
  #pragma unroll
  for (int fr = 0; fr < 2; ++fr)
    #pragma unroll
    for (int fc = 0; fc < 4; ++fc){ acc[fr][fc][0]=0.f; acc[fr][fc][1]=0.f; acc[fr][fc][2]=0.f; acc[fr][fc][3]=0.f; }
  #pragma unroll
  for (int ks = 0; ks < 5; ++ks){
    bf16x8 a[2];
    #pragma unroll
    for (int fr = 0; fr < 2; ++fr)
      a[fr] = *(const bf16x8*)&As[(wr*32 + fr*16 + q)*168 + ks*32 + kg8];
    #pragma unroll
    for (int fr = 0; fr < 2; ++fr)
      #pragma unroll
      for (int fc = 0; fc < 4; ++fc)
        acc[fr][fc] = __builtin_amdgcn_mfma_f32_16x16x32_bf16(a[fr], bfrag[ks][fc], acc[fr][fc], 0, 0, 0);
  }

  const float4 bb = *(const float4*)&bp0[wc*64 + q*4];
  #pragma unroll
  for (int fr = 0; fr < 2; ++fr){
    #pragma unroll
    for (int r = 0; r < 4; ++r){
      const int ee = e0 + wr*32 + fr*16 + (lane>>4)*4 + r;
      const int row = rankE[ee];
      ushort4 o;
      o.x = f2bf(lrelu(acc[fr][0][r] + bb.x));
      o.y = f2bf(lrelu(acc[fr][1][r] + bb.y));
      o.z = f2bf(lrelu(acc[fr][2][r] + bb.z));
      o.w = f2bf(lrelu(acc[fr][3][r] + bb.w));
      *(ushort4*)&h[(size_t)row*DH + wc*64 + q*4] = o;
    }
  }
}

// ================= agg[n] = sum of h' rows [offE[n], offE[n+1]) — 2 waves/node, 8-edge ILP =====
__global__ __launch_bounds__(256) void aggE_kernel(const u16* __restrict__ h, const int* __restrict__ off,
                                                   float* __restrict__ agg){
  const int t = threadIdx.x, lane = t & 63, wv = t >> 6;
  const int n = blockIdx.x*2 + (wv >> 1);
  const int half = wv & 1;
  const int lo = off[n], hi = off[n+1];
  const int c8 = half*64 + (lane & 7)*8, sub = lane >> 3;
  float a0=0,a1=0,a2=0,a3=0,a4=0,a5=0,a6=0,a7=0;
  for (int i = lo + sub; i < hi; i += 8){
    uint4 hv = *(const uint4*)&h[(size_t)i*DH + c8];
    a0 += bflo(hv.x); a1 += bfhi(hv.x); a2 += bflo(hv.y); a3 += bfhi(hv.y);
    a4 += bflo(hv.z); a5 += bfhi(hv.z); a6 += bflo(hv.w); a7 += bfhi(hv.w);
  }
  a0 += __shfl_xor(a0,8);  a1 += __shfl_xor(a1,8);  a2 += __shfl_xor(a2,8);  a3 += __shfl_xor(a3,8);
  a4 += __shfl_xor(a4,8);  a5 += __shfl_xor(a5,8);  a6 += __shfl_xor(a6,8);  a7 += __shfl_xor(a7,8);
  a0 += __shfl_xor(a0,16); a1 += __shfl_xor(a1,16); a2 += __shfl_xor(a2,16); a3 += __shfl_xor(a3,16);
  a4 += __shfl_xor(a4,16); a5 += __shfl_xor(a5,16); a6 += __shfl_xor(a6,16); a7 += __shfl_xor(a7,16);
  a0 += __shfl_xor(a0,32); a1 += __shfl_xor(a1,32); a2 += __shfl_xor(a2,32); a3 += __shfl_xor(a3,32);
  a4 += __shfl_xor(a4,32); a5 += __shfl_xor(a5,32); a6 += __shfl_xor(a6,32); a7 += __shfl_xor(a7,32);
  if (sub == 0){
    *(float4*)&agg[(size_t)n*DH + c8]     = make_float4(a0,a1,a2,a3);
    *(float4*)&agg[(size_t)n*DH + c8 + 4] = make_float4(a4,a5,a6,a7);
  }
}

// ================= P/Q GEMM: P = agg@W^T + b ; Q = h'[rankE[0:N]]@W^T  (pi space in/out) =====
__global__ __launch_bounds__(256) void pq_gemm(const float* __restrict__ agg, const u16* __restrict__ h,
                                               const int* __restrict__ rankE, const u16* __restrict__ Wb1,
                                               const float* __restrict__ bp1, float* __restrict__ P,
                                               float* __restrict__ Q){
  __shared__ u16 Alds[128][136];
  const int t = threadIdx.x, lane = t & 63, wv = t >> 6;
  const int wr = wv >> 1, wc = wv & 1;
  const int r0 = blockIdx.x * 128;
  const int q = lane & 15, kg8 = (lane >> 4)*8;

  bf16x8 bfrag[4][4];
  #pragma unroll
  for (int fc = 0; fc < 4; ++fc)
    #pragma unroll
    for (int ks = 0; ks < 4; ++ks)
      bfrag[ks][fc] = *(const bf16x8*)&Wb1[(size_t)(wc*64 + fc*16 + q)*128 + ks*32 + kg8];

  {
    const int rt = t >> 1, half = t & 1;
    const int gr = r0 + rt;
    u16* dst = &Alds[rt][half*64];
    if (gr < NN){
      const float4* src = (const float4*)&agg[(size_t)gr*DH + half*64];
      #pragma unroll
      for (int p = 0; p < 16; ++p){
        float4 x = src[p];
        ushort4 o; o.x=f2bf(x.x); o.y=f2bf(x.y); o.z=f2bf(x.z); o.w=f2bf(x.w);
        *(ushort4*)&dst[p*4] = o;
      }
    } else if (gr < 2*NN){
      const int row = rankE[gr - NN];
      const ushort4* src = (const ushort4*)&h[(size_t)row*DH + half*64];
      #pragma unroll
      for (int p = 0; p < 16; ++p) *(ushort4*)&dst[p*4] = src[p];
    } else {
      ushort4 z; z.x=0; z.y=0; z.z=0; z.w=0;
      #pragma unroll
      for (int p = 0; p < 16; ++p) *(ushort4*)&dst[p*4] = z;
    }
  }
  __syncthreads();

  f32x4 acc[4][4];
  #pragma unroll
  for (int fr = 0; fr < 4; ++fr)
    #pragma unroll
    for (int fc = 0; fc < 4; ++fc){ acc[fr][fc][0]=0.f; acc[fr][fc][1]=0.f; acc[fr][fc][2]=0.f; acc[fr][fc][3]=0.f; }
  #pragma unroll
  for (int ks = 0; ks < 4; ++ks){
    bf16x8 a[4];
    #pragma unroll
    for (int fr = 0; fr < 4; ++fr)
      a[fr] = *(const bf16x8*)&Alds[wr*64 + fr*16 + q][ks*32 + kg8];
    #pragma unroll
    for (int fr = 0; fr < 4; ++fr)
      #pragma unroll
      for (int fc = 0; fc < 4; ++fc)
        acc[fr][fc] = __builtin_amdgcn_mfma_f32_16x16x32_bf16(a[fr], bfrag[ks][fc], acc[fr][fc], 0, 0, 0);
  }

  const float4 bb = *(const float4*)&bp1[wc*64 + q*4];
  #pragma unroll
  for (int fr = 0; fr < 4; ++fr){
    #pragma unroll
    for (int r = 0; r < 4; ++r){
      const int grow = r0 + wr*64 + fr*16 + (lane>>4)*4 + r;
      if (grow < NN){
        float4 val = make_float4(acc[fr][0][r] + bb.x, acc[fr][1][r] + bb.y,
                                 acc[fr][2][r] + bb.z, acc[fr][3][r] + bb.w);
        *(float4*)&P[(size_t)grow*DH + wc*64 + q*4] = val;
      } else if (grow < 2*NN){
        float4 val = make_float4(acc[fr][0][r], acc[fr][1][r], acc[fr][2][r], acc[fr][3][r]);
        *(float4*)&Q[(size_t)(grow-NN)*DH + wc*64 + q*4] = val;
      }
    }
  }
}

// ===== middle layers: h'[i] = lrelu(h'[i] + P[srtE[i]] - Q[n]); agg[n]=sum — 2 waves/node, 8-ILP =====
__global__ __launch_bounds__(256) void fused_mid(u16* __restrict__ h, const float* __restrict__ P,
                                                 const float* __restrict__ Q, const int* __restrict__ srtE,
                                                 const int* __restrict__ off, float* __restrict__ agg){
  const int t = threadIdx.x, lane = t & 63, wv = t >> 6;
  const int n = blockIdx.x*2 + (wv >> 1);
  const int half = wv & 1;
  const int lo = off[n], hi = off[n+1];
  const int c8 = half*64 + (lane & 7)*8, sub = lane >> 3;
  const float4 q0 = *(const float4*)&Q[(size_t)n*DH + c8];
  const float4 q1 = *(const float4*)&Q[(size_t)n*DH + c8 + 4];
  float a0=0,a1=0,a2=0,a3=0,a4=0,a5=0,a6=0,a7=0;
  for (int i = lo + sub; i < hi; i += 8){
    const int s = srtE[i];
    uint4 hv = *(const uint4*)&h[(size_t)i*DH + c8];
    float4 p0 = *(const float4*)&P[(size_t)s*DH + c8];
    float4 p1 = *(const float4*)&P[(size_t)s*DH + c8 + 4];
    float v0 = lrelu(bflo(hv.x) + p0.x - q0.x);
    float v1 = lrelu(bfhi(hv.x) + p0.y - q0.y);
    float v2 = lrelu(bflo(hv.y) + p0.z - q0.z);
    float v3 = lrelu(bfhi(hv.y) + p0.w - q0.w);
    float v4 = lrelu(bflo(hv.z) + p1.x - q1.x);
    float v5 = lrelu(bfhi(hv.z) + p1.y - q1.y);
    float v6 = lrelu(bflo(hv.w) + p1.z - q1.z);
    float v7 = lrelu(bfhi(hv.w) + p1.w - q1.w);
    uint4 o;
    o.x = pk2(v0, v1); o.y = pk2(v2, v3); o.z = pk2(v4, v5); o.w = pk2(v6, v7);
    *(uint4*)&h[(size_t)i*DH + c8] = o;
    a0+=v0; a1+=v1; a2+=v2; a3+=v3; a4+=v4; a5+=v5; a6+=v6; a7+=v7;
  }
  a0 += __shfl_xor(a0,8);  a1 += __shfl_xor(a1,8);  a2 += __shfl_xor(a2,8);  a3 += __shfl_xor(a3,8);
  a4 += __shfl_xor(a4,8);  a5 += __shfl_xor(a5,8);  a6 += __shfl_xor(a6,8);  a7 += __shfl_xor(a7,8);
  a0 += __shfl_xor(a0,16); a1 += __shfl_xor(a1,16); a2 += __shfl_xor(a2,16); a3 += __shfl_xor(a3,16);
  a4 += __shfl_xor(a4,16); a5 += __shfl_xor(a5,16); a6 += __shfl_xor(a6,16); a7 += __shfl_xor(a7,16);
  a0 += __shfl_xor(a0,32); a1 += __shfl_xor(a1,32); a2 += __shfl_xor(a2,32); a3 += __shfl_xor(a3,32);
  a4 += __shfl_xor(a4,32); a5 += __shfl_xor(a5,32); a6 += __shfl_xor(a6,32); a7 += __shfl_xor(a7,32);
  if (sub == 0){
    *(float4*)&agg[(size_t)n*DH + c8]     = make_float4(a0,a1,a2,a3);
    *(float4*)&agg[(size_t)n*DH + c8 + 4] = make_float4(a4,a5,a6,a7);
  }
}

// ===== last layer: hnode[s] = sum over srt-CSR of lrelu(h'[listS2[i]] + P[s] - Q[endS[i]]) =====
__global__ __launch_bounds__(256) void fused_last(const u16* __restrict__ h, const float* __restrict__ P,
                                                  const float* __restrict__ Q, const int* __restrict__ endS,
                                                  const int* __restrict__ listS2, const int* __restrict__ off,
                                                  float* __restrict__ hnode){
  const int t = threadIdx.x, lane = t & 63, wv = t >> 6;
  const int s = blockIdx.x*2 + (wv >> 1);
  const int half = wv & 1;
  const int lo = off[s], hi = off[s+1];
  const int c8 = half*64 + (lane & 7)*8, sub = lane >> 3;
  const float4 p0 = *(const float4*)&P[(size_t)s*DH + c8];
  const float4 p1 = *(const float4*)&P[(size_t)s*DH + c8 + 4];
  float a0=0,a1=0,a2=0,a3=0,a4=0,a5=0,a6=0,a7=0;
  for (int i = lo + sub; i < hi; i += 8){
    const int row = listS2[i];
    const int d = endS[i];
    uint4 hv = *(const uint4*)&h[(size_t)row*DH + c8];
    float4 q0 = *(const float4*)&Q[(size_t)d*DH + c8];
    float4 q1 = *(const float4*)&Q[(size_t)d*DH + c8 + 4];
    a0 += lrelu(bflo(hv.x) + p0.x - q0.x);
    a1 += lrelu(bfhi(hv.x) + p0.y - q0.y);
    a2 += lrelu(bflo(hv.y) + p0.z - q0.z);
    a3 += lrelu(bfhi(hv.y) + p0.w - q0.w);
    a4 += lrelu(bflo(hv.z) + p1.x - q1.x);
    a5 += lrelu(bfhi(hv.z) + p1.y - q1.y);
    a6 += lrelu(bflo(hv.w) + p1.z - q1.z);
    a7 += lrelu(bfhi(hv.w) + p1.w - q1.w);
  }
  a0 += __shfl_xor(a0,8);  a1 += __shfl_xor(a1,8);  a2 += __shfl_xor(a2,8);  a3 += __shfl_xor(a3,8);
  a4 += __shfl_xor(a4,8);  a5 += __shfl_xor(a5,8);  a6 += __shfl_xor(a6,8);  a7 += __shfl_xor(a7,8);
  a0 += __shfl_xor(a0,16); a1 += __shfl_xor(a1,16); a2 += __shfl_xor(a2,16); a3 += __shfl_xor(a3,16);
  a4 += __shfl_xor(a4,16); a5 += __shfl_xor(a5,16); a6 += __shfl_xor(a6,16); a7 += __shfl_xor(a7,16);
  a0 += __shfl_xor(a0,32); a1 += __shfl_xor(a1,32); a2 += __shfl_xor(a2,32); a3 += __shfl_xor(a3,32);
  a4 += __shfl_xor(a4,32); a5 += __shfl_xor(a5,32); a6 += __shfl_xor(a6,32); a7 += __shfl_xor(a7,32);
  if (sub == 0){
    *(float4*)&hnode[(size_t)s*DH + c8]     = make_float4(a0,a1,a2,a3);
    *(float4*)&hnode[(size_t)s*DH + c8 + 4] = make_float4(a4,a5,a6,a7);
  }
}

// ================= nodes: atom = lrelu(hnode @ Wmol^T + b); normed = atom/||atom|| =================
// hnode columns are pi-permuted; permute Wmol's K during staging. Outputs canonical.
__global__ __launch_bounds__(256) void node_kernel(
    const float* __restrict__ hn, const float* __restrict__ W,
    const float* __restrict__ b, float* __restrict__ atom, float* __restrict__ normed)
{
  __shared__ float Wt[64*132];
  __shared__ float ms[32*DH];
  const int t = threadIdx.x;
  const int r0 = blockIdx.x * 32;
  const int jg = t & 31, eg = t >> 5;
  for (int idx = t; idx < 32*DH; idx += 256) {
    const int r = r0 + (idx >> 7);
    ms[idx] = (r < NN) ? hn[(size_t)r*DH + (idx & 127)] : 0.f;
  }
  float acc[4][4] = {};
  for (int c = 0; c < 2; ++c) {
    __syncthreads();
    for (int idx = t; idx < 128*64; idx += 256) {
      const int j = idx >> 6, kl = idx & 63;
      Wt[kl*132 + j] = W[j*DH + c*64 + ((kl&3)*16 + (kl>>2))];   // pi64 on K
    }
    __syncthreads();
    #pragma unroll 4
    for (int kl = 0; kl < 64; ++kl) {
      const float4 w = *(const float4*)&Wt[kl*132 + jg*4];
      const int kg = c*64 + kl;
      #pragma unroll
      for (int i = 0; i < 4; ++i) {
        const float mv = ms[(eg*4+i)*DH + kg];
        acc[i][0] += mv*w.x; acc[i][1] += mv*w.y; acc[i][2] += mv*w.z; acc[i][3] += mv*w.w;
      }
    }
  }
  float bj[4];
  #pragma unroll
  for (int c2 = 0; c2 < 4; ++c2) bj[c2] = b[jg*4 + c2];
  #pragma unroll
  for (int i = 0; i < 4; ++i) {
    const int r = r0 + eg*4 + i;
    float v[4]; float ss = 0.f;
    #pragma unroll
    for (int c2 = 0; c2 < 4; ++c2) { v[c2] = lrelu(acc[i][c2] + bj[c2]); ss += v[c2]*v[c2]; }
    ss += __shfl_xor(ss, 1); ss += __shfl_xor(ss, 2); ss += __shfl_xor(ss, 4);
    ss += __shfl_xor(ss, 8); ss += __shfl_xor(ss, 16);
    if (r < NN) {
      *(float4*)&atom[(size_t)r*DH + jg*4] = make_float4(v[0],v[1],v[2],v[3]);
      const float inv = 1.f / fmaxf(sqrtf(ss), 1e-12f);
      *(float4*)&normed[(size_t)r*DH + jg*4] = make_float4(v[0]*inv,v[1]*inv,v[2]*inv,v[3]*inv);
    }
  }
}

// ================= per-graph sum + out GEMV =================
__global__ __launch_bounds__(128) void graph_out_kernel(const float* __restrict__ normed, const int* __restrict__ batch,
                                                        const float* __restrict__ Wo, const float* __restrict__ bo,
                                                        float* __restrict__ out){
  const int g = blockIdx.x, t = threadIdx.x;
  int lo, hi;
  { int a=0, bb=NN; while(a<bb){ int m=(a+bb)>>1; if (batch[m] < g) a=m+1; else bb=m; } lo=a; }
  { int a=lo, bb=NN; while(a<bb){ int m=(a+bb)>>1; if (batch[m] < g+1) a=m+1; else bb=m; } hi=a; }
  float s = 0.f;
  for (int n = lo; n < hi; ++n) s += normed[(size_t)n*DH + t];
  float v = s * Wo[t];
  #pragma unroll
  for (int d2 = 1; d2 < 64; d2 <<= 1) v += __shfl_xor(v, d2);
  __shared__ float red[2];
  if ((t & 63) == 0) red[t >> 6] = v;
  __syncthreads();
  if (t == 0) out[g] = red[0] + red[1] + bo[0];
}

extern "C" void kernel_launch(void* const* d_in, const int* in_sizes, int n_in,
                              void* d_out, int out_size, void* d_ws, size_t ws_size,
                              hipStream_t stream)
{
  const float* cf     = (const float*)d_in[1];
  const int*   srt    = (const int*)d_in[2];
  const int*   endi   = (const int*)d_in[3];
  const int*   batch  = (const int*)d_in[5];
  const float* W_init = (const float*)d_in[6];
  const float* b_init = (const float*)d_in[7];
  const float* W_h1   = (const float*)d_in[8];
  const float* b_h1   = (const float*)d_in[9];
  const float* W_mol  = (const float*)d_in[10];
  const float* b_mol  = (const float*)d_in[11];
  const float* W_out  = (const float*)d_in[12];
  const float* b_out  = (const float*)d_in[13];

  float* out  = (float*)d_out;
  float* atom = out + NG;

  char* ws = (char*)d_ws;
  u16*   h      = (u16*)(ws);                    // 256,000,000 B (end-CSR rows, pi cols)
  float* agg    = (float*)(ws + 256000000);      // 25,600,000 B (pi cols)
  float* P      = (float*)(ws + 281600000);      // 25,600,000 B (pi cols)
  float* Q      = (float*)(ws + 307200000);      // 25,600,000 B (pi cols)
  int*   srtE   = (int*)(ws + 332800000);        // 4,000,000 B
  int*   endS   = (int*)(ws + 336800000);        // 4,000,000 B
  int*   rankE  = (int*)(ws + 340800000);        // 4,000,000 B
  int*   listS2 = (int*)(ws + 344800000);        // 4,000,000 B
  int*   offE   = (int*)(ws + 348800000);        // 200,704 B
  int*   offS   = (int*)(ws + 349000704);        // 200,704 B
  int*   curE   = (int*)(ws + 349201408);        // 200,704 B
  int*   curS   = (int*)(ws + 349402112);        // 200,704 B
  u16*   Wb1    = (u16*)(ws + 349602816);        // 32,768 B
  u16*   Wb0    = (u16*)(ws + 349635584);        // 40,960 B
  float* bp0    = (float*)(ws + 349676544);      // 512 B
  float* bp1    = (float*)(ws + 349677056);      // 512 B
  float* hnode  = agg;                           // agg dead after last pq_gemm
  float* normed = (float*)(ws);                  // reuse h region (h dead after fused_last)

  // ---- CSR build (int atomics only)
  hipMemsetAsync(curE, 0, 200704, stream);
  hipMemsetAsync(curS, 0, 200704, stream);
  hist_kernel<<<1024, 256, 0, stream>>>(endi, srt, curE, curS);
  scan2_kernel<<<2, 1024, 0, stream>>>(curE, offE, curS, offS);
  hipMemcpyAsync(curE, offE, (size_t)NN*4, hipMemcpyDeviceToDevice, stream);
  hipMemcpyAsync(curS, offS, (size_t)NN*4, hipMemcpyDeviceToDevice, stream);
  scatter_kernel<<<1024, 256, 0, stream>>>(endi, srt, curE, curS, rankE, srtE, listS2, endS);
  convertW_kernel<<<80, 256, 0, stream>>>(W_h1, W_init, b_init, b_h1, Wb1, Wb0, bp0, bp1);

  // ---- layer 0 (64-row tiles; writes h in end-CSR row order, pi col order)
  layer0_mfma<<<NE/64, 256, 0, stream>>>(cf, Wb0, bp0, rankE, h);
  aggE_kernel<<<NN/2, 256, 0, stream>>>(h, offE, agg);

  // ---- layers 1..2: tiny P/Q GEMMs + fused sequential update producing next agg
  for (int l = 0; l < 2; ++l){
    pq_gemm<<<(2*NN + 127)/128, 256, 0, stream>>>(agg, h, rankE, Wb1, bp1, P, Q);
    fused_mid<<<NN/2, 256, 0, stream>>>(h, P, Q, srtE, offE, agg);
  }
  // ---- layer 3: P/Q then direct hnode accumulation (no h write, no separate gather)
  pq_gemm<<<(2*NN + 127)/128, 256, 0, stream>>>(agg, h, rankE, Wb1, bp1, P, Q);
  fused_last<<<NN/2, 256, 0, stream>>>(h, P, Q, endS, listS2, offS, hnode);

  // ---- node MLP + normalize, per-graph sum + out
  node_kernel<<<(NN + 31)/32, 256, 0, stream>>>(hnode, W_mol, b_mol, atom, normed);
  graph_out_kernel<<<NG, 128, 0, stream>>>(normed, batch, W_out, b_out, out);
}

// Round 12
// 1037.647 us; speedup vs baseline: 1.4018x; 1.0799x over previous
//
#include <hip/hip_runtime.h>

#define NN 50000
#define NE 1000000
#define NG 1000
#define KE 147
#define DH 128

using u16 = unsigned short;
typedef __attribute__((ext_vector_type(8))) short bf16x8;
typedef __attribute__((ext_vector_type(4))) float f32x4;

__device__ __forceinline__ float lrelu(float v){ return fmaxf(v, 0.01f*v); }
__device__ __forceinline__ float bf2f(u16 u){ unsigned int x = ((unsigned int)u)<<16; float f; __builtin_memcpy(&f,&x,4); return f; }
__device__ __forceinline__ u16 f2bf(float f){ unsigned int x; __builtin_memcpy(&x,&f,4); x += 0x7fffu + ((x>>16)&1u); return (u16)(x>>16); }
__device__ __forceinline__ float bflo(unsigned w){ unsigned x = w<<16; float f; __builtin_memcpy(&f,&x,4); return f; }
__device__ __forceinline__ float bfhi(unsigned w){ unsigned x = w & 0xffff0000u; float f; __builtin_memcpy(&f,&x,4); return f; }
__device__ __forceinline__ unsigned pk2(float lo, float hi){ return ((unsigned)f2bf(hi)<<16) | (unsigned)f2bf(lo); }
// column permutation: memory position p holds logical column cpi(p)
__device__ __host__ __forceinline__ int cpi(int p){ return (p & 64) | ((p & 3) << 4) | ((p & 63) >> 2); }

// ================= CSR build =================
__global__ __launch_bounds__(256) void hist_kernel(const int* __restrict__ endi, const int* __restrict__ srt,
                                                   int* __restrict__ cntE, int* __restrict__ cntS){
  for (int i = blockIdx.x*256 + threadIdx.x; i < NE; i += gridDim.x*256){
    atomicAdd(&cntE[endi[i]], 1);
    atomicAdd(&cntS[srt[i]], 1);
  }
}

__global__ __launch_bounds__(1024) void scan2_kernel(const int* __restrict__ cntE, int* __restrict__ offE,
                                                     const int* __restrict__ cntS, int* __restrict__ offS){
  const int* deg = blockIdx.x ? cntS : cntE;
  int* off = blockIdx.x ? offS : offE;
  __shared__ int wsum[17];
  const int t = threadIdx.x, lane = t & 63, wv = t >> 6;
  int carry = 0;
  for (int base = 0; base < 50176; base += 1024){
    const int i = base + t;
    int v = (i < NN) ? deg[i] : 0;
    int s = v;
    #pragma unroll
    for (int d = 1; d < 64; d <<= 1){
      int x = __shfl_up(s, d);
      if (lane >= d) s += x;
    }
    if (lane == 63) wsum[wv] = s;
    __syncthreads();
    if (t == 0){
      int run = 0;
      #pragma unroll
      for (int k = 0; k < 16; ++k){ int x = wsum[k]; wsum[k] = run; run += x; }
      wsum[16] = run;
    }
    __syncthreads();
    if (i <= NN) off[i] = carry + wsum[wv] + s - v;
    carry += wsum[16];
    __syncthreads();
  }
}

// scatter: rankE (edge->permuted row), srtE (per row), listS2 (srt-CSR -> permuted row), endS
__global__ __launch_bounds__(256) void scatter_kernel(const int* __restrict__ endi, const int* __restrict__ srt,
                                                      int* __restrict__ curE, int* __restrict__ curS,
                                                      int* __restrict__ rankE, int* __restrict__ srtE,
                                                      int* __restrict__ listS2, int* __restrict__ endS){
  for (int i = blockIdx.x*256 + threadIdx.x; i < NE; i += gridDim.x*256){
    const int e = endi[i], s = srt[i];
    int p = atomicAdd(&curE[e], 1);
    rankE[i] = p; srtE[p] = s;
    int q = atomicAdd(&curS[s], 1);
    listS2[q] = p; endS[q] = e;
  }
}

// Wb0: natural layout padded K=160. Wb1: K permuted by cpi. bp0/bp1: biases permuted by cpi.
__global__ __launch_bounds__(256) void convertW_kernel(const float* __restrict__ W1, const float* __restrict__ W0,
                                                       const float* __restrict__ b0, const float* __restrict__ b1,
                                                       u16* __restrict__ Wb1, u16* __restrict__ Wb0,
                                                       float* __restrict__ bp0, float* __restrict__ bp1){
  int i = blockIdx.x*256 + threadIdx.x;
  if (i < 128*128){
    int j = i >> 7, k = i & 127;
    Wb1[i] = f2bf(W1[j*DH + cpi(k)]);
  }
  if (i < 128*160){
    int j = i/160, k = i - j*160;
    Wb0[i] = (k < KE) ? f2bf(W0[j*KE + k]) : (u16)0;
  }
  if (i < 128){ bp0[i] = b0[cpi(i)]; bp1[i] = b1[cpi(i)]; }
}

// ================= layer 0: h'[rankE[e]] = lrelu(cf[e] @ W0^T + b) =================
// 64-row tile (21.5 KB LDS -> 7 blocks/CU by LDS), NE % 64 == 0 so no tail guards.
__global__ __launch_bounds__(256) void layer0_mfma(const float* __restrict__ cf, const u16* __restrict__ Wb0,
                                                   const float* __restrict__ bp0, const int* __restrict__ rankE,
                                                   u16* __restrict__ h){
  __shared__ __align__(16) u16 As[64*168];    // 21,504 B
  const int t = threadIdx.x, lane = t & 63, wv = t >> 6;
  const int wr = wv >> 1, wc = wv & 1;
  const int e0 = blockIdx.x * 64;
  const int q = lane & 15, kg8 = (lane >> 4)*8;

  bf16x8 bfrag[5][4];
  #pragma unroll
  for (int fc = 0; fc < 4; ++fc)
    #pragma unroll
    for (int ks = 0; ks < 5; ++ks)
      bfrag[ks][fc] = *(const bf16x8*)&Wb0[(size_t)(wc*64 + fc*16 + q)*160 + ks*32 + kg8];

  {
    const float4* src = (const float4*)(cf + (size_t)e0*KE);   // 64*147*4 B, base 16B-aligned
    #pragma unroll
    for (int k = 0; k < 10; ++k){
      const int i4 = t + k*256;
      if (i4 < 2352){                         // 64*147/4
        float4 v = src[i4];
        const int g = i4*4;
        int r = (unsigned)g / 147u;
        int c = g - r*147;
        u16 w0 = f2bf(v.x), w1 = f2bf(v.y), w2 = f2bf(v.z), w3 = f2bf(v.w);
        As[r*168 + c] = w0; if (++c == 147){ c = 0; ++r; }
        As[r*168 + c] = w1; if (++c == 147){ c = 0; ++r; }
        As[r*168 + c] = w2; if (++c == 147){ c = 0; ++r; }
        As[r*168 + c] = w3;
      }
    }
  }
  // zero pad cols 147..159 (ks=4 reads them; keep zeroed)
  for (int idx = t; idx < 64*16; idx += 256){
    const int r = idx >> 4, c = idx & 15;
    if (c < 13) As[r*168 + 147 + c] = 0;
  }
  __syncthreads();

  f32x4 acc[2][4];
  #pragma unroll
  for (int fr = 0; fr < 2; ++fr)
    #pragma unroll
    for (int fc = 0; fc < 4; ++fc){ acc[fr][fc][0]=0.f; acc[fr][fc][1]=0.f; acc[fr][fc][2]=0.f; acc[fr][fc][3]=0.f; }
  #pragma unroll
  for (int ks = 0; ks < 5; ++ks){
    bf16x8 a[2];
    #pragma unroll
    for (int fr = 0; fr < 2; ++fr)
      a[fr] = *(const bf16x8*)&As[(wr*32 + fr*16 + q)*168 + ks*32 + kg8];
    #pragma unroll
    for (int fr = 0; fr < 2; ++fr)
      #pragma unroll
      for (int fc = 0; fc < 4; ++fc)
        acc[fr][fc] = __builtin_amdgcn_mfma_f32_16x16x32_bf16(a[fr], bfrag[ks][fc], acc[fr][fc], 0, 0, 0);
  }

  const float4 bb = *(const float4*)&bp0[wc*64 + q*4];
  #pragma unroll
  for (int fr = 0; fr < 2; ++fr){
    #pragma unroll
    for (int r = 0; r < 4; ++r){
      const int ee = e0 + wr*32 + fr*16 + (lane>>4)*4 + r;
      const int row = rankE[ee];
      ushort4 o;
      o.x = f2bf(lrelu(acc[fr][0][r] + bb.x));
      o.y = f2bf(lrelu(acc[fr][1][r] + bb.y));
      o.z = f2bf(lrelu(acc[fr][2][r] + bb.z));
      o.w = f2bf(lrelu(acc[fr][3][r] + bb.w));
      *(ushort4*)&h[(size_t)row*DH + wc*64 + q*4] = o;
    }
  }
}

// ================= agg[n] = sum of h' rows [offE[n], offE[n+1]) — 2 waves/node, 8-edge ILP =====
__global__ __launch_bounds__(256) void aggE_kernel(const u16* __restrict__ h, const int* __restrict__ off,
                                                   float* __restrict__ agg){
  const int t = threadIdx.x, lane = t & 63, wv = t >> 6;
  const int n = blockIdx.x*2 + (wv >> 1);
  const int half = wv & 1;
  const int lo = off[n], hi = off[n+1];
  const int c8 = half*64 + (lane & 7)*8, sub = lane >> 3;
  float a0=0,a1=0,a2=0,a3=0,a4=0,a5=0,a6=0,a7=0;
  for (int i = lo + sub; i < hi; i += 8){
    uint4 hv = *(const uint4*)&h[(size_t)i*DH + c8];
    a0 += bflo(hv.x); a1 += bfhi(hv.x); a2 += bflo(hv.y); a3 += bfhi(hv.y);
    a4 += bflo(hv.z); a5 += bfhi(hv.z); a6 += bflo(hv.w); a7 += bfhi(hv.w);
  }
  a0 += __shfl_xor(a0,8);  a1 += __shfl_xor(a1,8);  a2 += __shfl_xor(a2,8);  a3 += __shfl_xor(a3,8);
  a4 += __shfl_xor(a4,8);  a5 += __shfl_xor(a5,8);  a6 += __shfl_xor(a6,8);  a7 += __shfl_xor(a7,8);
  a0 += __shfl_xor(a0,16); a1 += __shfl_xor(a1,16); a2 += __shfl_xor(a2,16); a3 += __shfl_xor(a3,16);
  a4 += __shfl_xor(a4,16); a5 += __shfl_xor(a5,16); a6 += __shfl_xor(a6,16); a7 += __shfl_xor(a7,16);
  a0 += __shfl_xor(a0,32); a1 += __shfl_xor(a1,32); a2 += __shfl_xor(a2,32); a3 += __shfl_xor(a3,32);
  a4 += __shfl_xor(a4,32); a5 += __shfl_xor(a5,32); a6 += __shfl_xor(a6,32); a7 += __shfl_xor(a7,32);
  if (sub == 0){
    *(float4*)&agg[(size_t)n*DH + c8]     = make_float4(a0,a1,a2,a3);
    *(float4*)&agg[(size_t)n*DH + c8 + 4] = make_float4(a4,a5,a6,a7);
  }
}

// ========== P/Q GEMM: P = bf16(agg@W^T + b) ; Q = bf16(h'[rankE[0:N]]@W^T)  (pi space, bf16 out) =====
__global__ __launch_bounds__(256) void pq_gemm(const float* __restrict__ agg, const u16* __restrict__ h,
                                               const int* __restrict__ rankE, const u16* __restrict__ Wb1,
                                               const float* __restrict__ bp1, u16* __restrict__ P,
                                               u16* __restrict__ Q){
  __shared__ u16 Alds[128][136];
  const int t = threadIdx.x, lane = t & 63, wv = t >> 6;
  const int wr = wv >> 1, wc = wv & 1;
  const int r0 = blockIdx.x * 128;
  const int q = lane & 15, kg8 = (lane >> 4)*8;

  bf16x8 bfrag[4][4];
  #pragma unroll
  for (int fc = 0; fc < 4; ++fc)
    #pragma unroll
    for (int ks = 0; ks < 4; ++ks)
      bfrag[ks][fc] = *(const bf16x8*)&Wb1[(size_t)(wc*64 + fc*16 + q)*128 + ks*32 + kg8];

  {
    const int rt = t >> 1, half = t & 1;
    const int gr = r0 + rt;
    u16* dst = &Alds[rt][half*64];
    if (gr < NN){
      const float4* src = (const float4*)&agg[(size_t)gr*DH + half*64];
      #pragma unroll
      for (int p = 0; p < 16; ++p){
        float4 x = src[p];
        ushort4 o; o.x=f2bf(x.x); o.y=f2bf(x.y); o.z=f2bf(x.z); o.w=f2bf(x.w);
        *(ushort4*)&dst[p*4] = o;
      }
    } else if (gr < 2*NN){
      const int row = rankE[gr - NN];
      const ushort4* src = (const ushort4*)&h[(size_t)row*DH + half*64];
      #pragma unroll
      for (int p = 0; p < 16; ++p) *(ushort4*)&dst[p*4] = src[p];
    } else {
      ushort4 z; z.x=0; z.y=0; z.z=0; z.w=0;
      #pragma unroll
      for (int p = 0; p < 16; ++p) *(ushort4*)&dst[p*4] = z;
    }
  }
  __syncthreads();

  f32x4 acc[4][4];
  #pragma unroll
  for (int fr = 0; fr < 4; ++fr)
    #pragma unroll
    for (int fc = 0; fc < 4; ++fc){ acc[fr][fc][0]=0.f; acc[fr][fc][1]=0.f; acc[fr][fc][2]=0.f; acc[fr][fc][3]=0.f; }
  #pragma unroll
  for (int ks = 0; ks < 4; ++ks){
    bf16x8 a[4];
    #pragma unroll
    for (int fr = 0; fr < 4; ++fr)
      a[fr] = *(const bf16x8*)&Alds[wr*64 + fr*16 + q][ks*32 + kg8];
    #pragma unroll
    for (int fr = 0; fr < 4; ++fr)
      #pragma unroll
      for (int fc = 0; fc < 4; ++fc)
        acc[fr][fc] = __builtin_amdgcn_mfma_f32_16x16x32_bf16(a[fr], bfrag[ks][fc], acc[fr][fc], 0, 0, 0);
  }

  const float4 bb = *(const float4*)&bp1[wc*64 + q*4];
  #pragma unroll
  for (int fr = 0; fr < 4; ++fr){
    #pragma unroll
    for (int r = 0; r < 4; ++r){
      const int grow = r0 + wr*64 + fr*16 + (lane>>4)*4 + r;
      if (grow < NN){
        ushort4 o;
        o.x = f2bf(acc[fr][0][r] + bb.x);
        o.y = f2bf(acc[fr][1][r] + bb.y);
        o.z = f2bf(acc[fr][2][r] + bb.z);
        o.w = f2bf(acc[fr][3][r] + bb.w);
        *(ushort4*)&P[(size_t)grow*DH + wc*64 + q*4] = o;
      } else if (grow < 2*NN){
        ushort4 o;
        o.x = f2bf(acc[fr][0][r]);
        o.y = f2bf(acc[fr][1][r]);
        o.z = f2bf(acc[fr][2][r]);
        o.w = f2bf(acc[fr][3][r]);
        *(ushort4*)&Q[(size_t)(grow-NN)*DH + wc*64 + q*4] = o;
      }
    }
  }
}

// ===== middle layers: h'[i] = lrelu(h'[i] + P[srtE[i]] - Q[n]); agg[n]=sum — bf16 P/Q, 8-ILP =====
__global__ __launch_bounds__(256) void fused_mid(u16* __restrict__ h, const u16* __restrict__ P,
                                                 const u16* __restrict__ Q, const int* __restrict__ srtE,
                                                 const int* __restrict__ off, float* __restrict__ agg){
  const int t = threadIdx.x, lane = t & 63, wv = t >> 6;
  const int n = blockIdx.x*2 + (wv >> 1);
  const int half = wv & 1;
  const int lo = off[n], hi = off[n+1];
  const int c8 = half*64 + (lane & 7)*8, sub = lane >> 3;
  const uint4 qw = *(const uint4*)&Q[(size_t)n*DH + c8];
  const float q0 = bflo(qw.x), q1 = bfhi(qw.x), q2 = bflo(qw.y), q3 = bfhi(qw.y);
  const float q4 = bflo(qw.z), q5 = bfhi(qw.z), q6 = bflo(qw.w), q7 = bfhi(qw.w);
  float a0=0,a1=0,a2=0,a3=0,a4=0,a5=0,a6=0,a7=0;
  for (int i = lo + sub; i < hi; i += 8){
    const int s = srtE[i];
    uint4 hv = *(const uint4*)&h[(size_t)i*DH + c8];
    uint4 pw = *(const uint4*)&P[(size_t)s*DH + c8];
    float v0 = lrelu(bflo(hv.x) + bflo(pw.x) - q0);
    float v1 = lrelu(bfhi(hv.x) + bfhi(pw.x) - q1);
    float v2 = lrelu(bflo(hv.y) + bflo(pw.y) - q2);
    float v3 = lrelu(bfhi(hv.y) + bfhi(pw.y) - q3);
    float v4 = lrelu(bflo(hv.z) + bflo(pw.z) - q4);
    float v5 = lrelu(bfhi(hv.z) + bfhi(pw.z) - q5);
    float v6 = lrelu(bflo(hv.w) + bflo(pw.w) - q6);
    float v7 = lrelu(bfhi(hv.w) + bfhi(pw.w) - q7);
    uint4 o;
    o.x = pk2(v0, v1); o.y = pk2(v2, v3); o.z = pk2(v4, v5); o.w = pk2(v6, v7);
    *(uint4*)&h[(size_t)i*DH + c8] = o;
    a0+=v0; a1+=v1; a2+=v2; a3+=v3; a4+=v4; a5+=v5; a6+=v6; a7+=v7;
  }
  a0 += __shfl_xor(a0,8);  a1 += __shfl_xor(a1,8);  a2 += __shfl_xor(a2,8);  a3 += __shfl_xor(a3,8);
  a4 += __shfl_xor(a4,8);  a5 += __shfl_xor(a5,8);  a6 += __shfl_xor(a6,8);  a7 += __shfl_xor(a7,8);
  a0 += __shfl_xor(a0,16); a1 += __shfl_xor(a1,16); a2 += __shfl_xor(a2,16); a3 += __shfl_xor(a3,16);
  a4 += __shfl_xor(a4,16); a5 += __shfl_xor(a5,16); a6 += __shfl_xor(a6,16); a7 += __shfl_xor(a7,16);
  a0 += __shfl_xor(a0,32); a1 += __shfl_xor(a1,32); a2 += __shfl_xor(a2,32); a3 += __shfl_xor(a3,32);
  a4 += __shfl_xor(a4,32); a5 += __shfl_xor(a5,32); a6 += __shfl_xor(a6,32); a7 += __shfl_xor(a7,32);
  if (sub == 0){
    *(float4*)&agg[(size_t)n*DH + c8]     = make_float4(a0,a1,a2,a3);
    *(float4*)&agg[(size_t)n*DH + c8 + 4] = make_float4(a4,a5,a6,a7);
  }
}

// ===== last layer: hnode[s] = sum over srt-CSR of lrelu(h'[listS2[i]] + P[s] - Q[endS[i]]) =====
__global__ __launch_bounds__(256) void fused_last(const u16* __restrict__ h, const u16* __restrict__ P,
                                                  const u16* __restrict__ Q, const int* __restrict__ endS,
                                                  const int* __restrict__ listS2, const int* __restrict__ off,
                                                  float* __restrict__ hnode){
  const int t = threadIdx.x, lane = t & 63, wv = t >> 6;
  const int s = blockIdx.x*2 + (wv >> 1);
  const int half = wv & 1;
  const int lo = off[s], hi = off[s+1];
  const int c8 = half*64 + (lane & 7)*8, sub = lane >> 3;
  const uint4 pw = *(const uint4*)&P[(size_t)s*DH + c8];
  const float p0 = bflo(pw.x), p1 = bfhi(pw.x), p2 = bflo(pw.y), p3 = bfhi(pw.y);
  const float p4 = bflo(pw.z), p5 = bfhi(pw.z), p6 = bflo(pw.w), p7 = bfhi(pw.w);
  float a0=0,a1=0,a2=0,a3=0,a4=0,a5=0,a6=0,a7=0;
  for (int i = lo + sub; i < hi; i += 8){
    const int row = listS2[i];
    const int d = endS[i];
    uint4 hv = *(const uint4*)&h[(size_t)row*DH + c8];
    uint4 qw = *(const uint4*)&Q[(size_t)d*DH + c8];
    a0 += lrelu(bflo(hv.x) + p0 - bflo(qw.x));
    a1 += lrelu(bfhi(hv.x) + p1 - bfhi(qw.x));
    a2 += lrelu(bflo(hv.y) + p2 - bflo(qw.y));
    a3 += lrelu(bfhi(hv.y) + p3 - bfhi(qw.y));
    a4 += lrelu(bflo(hv.z) + p4 - bflo(qw.z));
    a5 += lrelu(bfhi(hv.z) + p5 - bfhi(qw.z));
    a6 += lrelu(bflo(hv.w) + p6 - bflo(qw.w));
    a7 += lrelu(bfhi(hv.w) + p7 - bfhi(qw.w));
  }
  a0 += __shfl_xor(a0,8);  a1 += __shfl_xor(a1,8);  a2 += __shfl_xor(a2,8);  a3 += __shfl_xor(a3,8);
  a4 += __shfl_xor(a4,8);  a5 += __shfl_xor(a5,8);  a6 += __shfl_xor(a6,8);  a7 += __shfl_xor(a7,8);
  a0 += __shfl_xor(a0,16); a1 += __shfl_xor(a1,16); a2 += __shfl_xor(a2,16); a3 += __shfl_xor(a3,16);
  a4 += __shfl_xor(a4,16); a5 += __shfl_xor(a5,16); a6 += __shfl_xor(a6,16); a7 += __shfl_xor(a7,16);
  a0 += __shfl_xor(a0,32); a1 += __shfl_xor(a1,32); a2 += __shfl_xor(a2,32); a3 += __shfl_xor(a3,32);
  a4 += __shfl_xor(a4,32); a5 += __shfl_xor(a5,32); a6 += __shfl_xor(a6,32); a7 += __shfl_xor(a7,32);
  if (sub == 0){
    *(float4*)&hnode[(size_t)s*DH + c8]     = make_float4(a0,a1,a2,a3);
    *(float4*)&hnode[(size_t)s*DH + c8 + 4] = make_float4(a4,a5,a6,a7);
  }
}

// ================= nodes: atom = lrelu(hnode @ Wmol^T + b); normed = atom/||atom|| =================
// hnode columns are pi-permuted; permute Wmol's K during staging. Outputs canonical.
__global__ __launch_bounds__(256) void node_kernel(
    const float* __restrict__ hn, const float* __restrict__ W,
    const float* __restrict__ b, float* __restrict__ atom, float* __restrict__ normed)
{
  __shared__ float Wt[64*132];
  __shared__ float ms[32*DH];
  const int t = threadIdx.x;
  const int r0 = blockIdx.x * 32;
  const int jg = t & 31, eg = t >> 5;
  for (int idx = t; idx < 32*DH; idx += 256) {
    const int r = r0 + (idx >> 7);
    ms[idx] = (r < NN) ? hn[(size_t)r*DH + (idx & 127)] : 0.f;
  }
  float acc[4][4] = {};
  for (int c = 0; c < 2; ++c) {
    __syncthreads();
    for (int idx = t; idx < 128*64; idx += 256) {
      const int j = idx >> 6, kl = idx & 63;
      Wt[kl*132 + j] = W[j*DH + c*64 + ((kl&3)*16 + (kl>>2))];   // pi64 on K
    }
    __syncthreads();
    #pragma unroll 4
    for (int kl = 0; kl < 64; ++kl) {
      const float4 w = *(const float4*)&Wt[kl*132 + jg*4];
      const int kg = c*64 + kl;
      #pragma unroll
      for (int i = 0; i < 4; ++i) {
        const float mv = ms[(eg*4+i)*DH + kg];
        acc[i][0] += mv*w.x; acc[i][1] += mv*w.y; acc[i][2] += mv*w.z; acc[i][3] += mv*w.w;
      }
    }
  }
  float bj[4];
  #pragma unroll
  for (int c2 = 0; c2 < 4; ++c2) bj[c2] = b[jg*4 + c2];
  #pragma unroll
  for (int i = 0; i < 4; ++i) {
    const int r = r0 + eg*4 + i;
    float v[4]; float ss = 0.f;
    #pragma unroll
    for (int c2 = 0; c2 < 4; ++c2) { v[c2] = lrelu(acc[i][c2] + bj[c2]); ss += v[c2]*v[c2]; }
    ss += __shfl_xor(ss, 1); ss += __shfl_xor(ss, 2); ss += __shfl_xor(ss, 4);
    ss += __shfl_xor(ss, 8); ss += __shfl_xor(ss, 16);
    if (r < NN) {
      *(float4*)&atom[(size_t)r*DH + jg*4] = make_float4(v[0],v[1],v[2],v[3]);
      const float inv = 1.f / fmaxf(sqrtf(ss), 1e-12f);
      *(float4*)&normed[(size_t)r*DH + jg*4] = make_float4(v[0]*inv,v[1]*inv,v[2]*inv,v[3]*inv);
    }
  }
}

// ================= per-graph sum + out GEMV =================
__global__ __launch_bounds__(128) void graph_out_kernel(const float* __restrict__ normed, const int* __restrict__ batch,
                                                        const float* __restrict__ Wo, const float* __restrict__ bo,
                                                        float* __restrict__ out){
  const int g = blockIdx.x, t = threadIdx.x;
  int lo, hi;
  { int a=0, bb=NN; while(a<bb){ int m=(a+bb)>>1; if (batch[m] < g) a=m+1; else bb=m; } lo=a; }
  { int a=lo, bb=NN; while(a<bb){ int m=(a+bb)>>1; if (batch[m] < g+1) a=m+1; else bb=m; } hi=a; }
  float s = 0.f;
  for (int n = lo; n < hi; ++n) s += normed[(size_t)n*DH + t];
  float v = s * Wo[t];
  #pragma unroll
  for (int d2 = 1; d2 < 64; d2 <<= 1) v += __shfl_xor(v, d2);
  __shared__ float red[2];
  if ((t & 63) == 0) red[t >> 6] = v;
  __syncthreads();
  if (t == 0) out[g] = red[0] + red[1] + bo[0];
}

extern "C" void kernel_launch(void* const* d_in, const int* in_sizes, int n_in,
                              void* d_out, int out_size, void* d_ws, size_t ws_size,
                              hipStream_t stream)
{
  const float* cf     = (const float*)d_in[1];
  const int*   srt    = (const int*)d_in[2];
  const int*   endi   = (const int*)d_in[3];
  const int*   batch  = (const int*)d_in[5];
  const float* W_init = (const float*)d_in[6];
  const float* b_init = (const float*)d_in[7];
  const float* W_h1   = (const float*)d_in[8];
  const float* b_h1   = (const float*)d_in[9];
  const float* W_mol  = (const float*)d_in[10];
  const float* b_mol  = (const float*)d_in[11];
  const float* W_out  = (const float*)d_in[12];
  const float* b_out  = (const float*)d_in[13];

  float* out  = (float*)d_out;
  float* atom = out + NG;

  char* ws = (char*)d_ws;
  u16*   h      = (u16*)(ws);                    // 256,000,000 B (end-CSR rows, pi cols)
  float* agg    = (float*)(ws + 256000000);      // 25,600,000 B (pi cols)
  u16*   P      = (u16*)(ws + 281600000);        // 12,800,000 B (pi cols, bf16)
  u16*   Q      = (u16*)(ws + 307200000);        // 12,800,000 B (pi cols, bf16)
  int*   srtE   = (int*)(ws + 332800000);        // 4,000,000 B
  int*   endS   = (int*)(ws + 336800000);        // 4,000,000 B
  int*   rankE  = (int*)(ws + 340800000);        // 4,000,000 B
  int*   listS2 = (int*)(ws + 344800000);        // 4,000,000 B
  int*   offE   = (int*)(ws + 348800000);        // 200,704 B
  int*   offS   = (int*)(ws + 349000704);        // 200,704 B
  int*   curE   = (int*)(ws + 349201408);        // 200,704 B
  int*   curS   = (int*)(ws + 349402112);        // 200,704 B
  u16*   Wb1    = (u16*)(ws + 349602816);        // 32,768 B
  u16*   Wb0    = (u16*)(ws + 349635584);        // 40,960 B
  float* bp0    = (float*)(ws + 349676544);      // 512 B
  float* bp1    = (float*)(ws + 349677056);      // 512 B
  float* hnode  = agg;                           // agg dead after last pq_gemm
  float* normed = (float*)(ws);                  // reuse h region (h dead after fused_last)

  // ---- CSR build (int atomics only)
  hipMemsetAsync(curE, 0, 200704, stream);
  hipMemsetAsync(curS, 0, 200704, stream);
  hist_kernel<<<1024, 256, 0, stream>>>(endi, srt, curE, curS);
  scan2_kernel<<<2, 1024, 0, stream>>>(curE, offE, curS, offS);
  hipMemcpyAsync(curE, offE, (size_t)NN*4, hipMemcpyDeviceToDevice, stream);
  hipMemcpyAsync(curS, offS, (size_t)NN*4, hipMemcpyDeviceToDevice, stream);
  scatter_kernel<<<1024, 256, 0, stream>>>(endi, srt, curE, curS, rankE, srtE, listS2, endS);
  convertW_kernel<<<80, 256, 0, stream>>>(W_h1, W_init, b_init, b_h1, Wb1, Wb0, bp0, bp1);

  // ---- layer 0 (64-row tiles; writes h in end-CSR row order, pi col order)
  layer0_mfma<<<NE/64, 256, 0, stream>>>(cf, Wb0, bp0, rankE, h);
  aggE_kernel<<<NN/2, 256, 0, stream>>>(h, offE, agg);

  // ---- layers 1..2: tiny P/Q GEMMs (bf16 out) + fused sequential update producing next agg
  for (int l = 0; l < 2; ++l){
    pq_gemm<<<(2*NN + 127)/128, 256, 0, stream>>>(agg, h, rankE, Wb1, bp1, P, Q);
    fused_mid<<<NN/2, 256, 0, stream>>>(h, P, Q, srtE, offE, agg);
  }
  // ---- layer 3: P/Q then direct hnode accumulation (no h write, no separate gather)
  pq_gemm<<<(2*NN + 127)/128, 256, 0, stream>>>(agg, h, rankE, Wb1, bp1, P, Q);
  fused_last<<<NN/2, 256, 0, stream>>>(h, P, Q, endS, listS2, offS, hnode);

  // ---- node MLP + normalize, per-graph sum + out
  node_kernel<<<(NN + 31)/32, 256, 0, stream>>>(hnode, W_mol, b_mol, atom, normed);
  graph_out_kernel<<<NG, 128, 0, stream>>>(normed, batch, W_out, b_out, out);
}

// Round 13
// 1036.990 us; speedup vs baseline: 1.4026x; 1.0006x over previous
//
#include <hip/hip_runtime.h>

#define NN 50000
#define NE 1000000
#define NG 1000
#define KE 147
#define DH 128

using u16 = unsigned short;
typedef __attribute__((ext_vector_type(8))) short bf16x8;
typedef __attribute__((ext_vector_type(4))) float f32x4;

__device__ __forceinline__ float lrelu(float v){ return fmaxf(v, 0.01f*v); }
__device__ __forceinline__ float bf2f(u16 u){ unsigned int x = ((unsigned int)u)<<16; float f; __builtin_memcpy(&f,&x,4); return f; }
__device__ __forceinline__ u16 f2bf(float f){ unsigned int x; __builtin_memcpy(&x,&f,4); x += 0x7fffu + ((x>>16)&1u); return (u16)(x>>16); }
__device__ __forceinline__ float bflo(unsigned w){ unsigned x = w<<16; float f; __builtin_memcpy(&f,&x,4); return f; }
__device__ __forceinline__ float bfhi(unsigned w){ unsigned x = w & 0xffff0000u; float f; __builtin_memcpy(&f,&x,4); return f; }
__device__ __forceinline__ unsigned pk2(float lo, float hi){ return ((unsigned)f2bf(hi)<<16) | (unsigned)f2bf(lo); }
// column permutation: memory position p holds logical column cpi(p)
__device__ __host__ __forceinline__ int cpi(int p){ return (p & 64) | ((p & 3) << 4) | ((p & 63) >> 2); }

// ================= CSR build =================
__global__ __launch_bounds__(256) void hist_kernel(const int* __restrict__ endi, const int* __restrict__ srt,
                                                   int* __restrict__ cntE, int* __restrict__ cntS){
  for (int i = blockIdx.x*256 + threadIdx.x; i < NE; i += gridDim.x*256){
    atomicAdd(&cntE[endi[i]], 1);
    atomicAdd(&cntS[srt[i]], 1);
  }
}

__global__ __launch_bounds__(1024) void scan2_kernel(const int* __restrict__ cntE, int* __restrict__ offE,
                                                     const int* __restrict__ cntS, int* __restrict__ offS){
  const int* deg = blockIdx.x ? cntS : cntE;
  int* off = blockIdx.x ? offS : offE;
  __shared__ int wsum[17];
  const int t = threadIdx.x, lane = t & 63, wv = t >> 6;
  int carry = 0;
  for (int base = 0; base < 50176; base += 1024){
    const int i = base + t;
    int v = (i < NN) ? deg[i] : 0;
    int s = v;
    #pragma unroll
    for (int d = 1; d < 64; d <<= 1){
      int x = __shfl_up(s, d);
      if (lane >= d) s += x;
    }
    if (lane == 63) wsum[wv] = s;
    __syncthreads();
    if (t == 0){
      int run = 0;
      #pragma unroll
      for (int k = 0; k < 16; ++k){ int x = wsum[k]; wsum[k] = run; run += x; }
      wsum[16] = run;
    }
    __syncthreads();
    if (i <= NN) off[i] = carry + wsum[wv] + s - v;
    carry += wsum[16];
    __syncthreads();
  }
}

// scatter: rankE (edge->permuted row), srtE (per row), listS2 (srt-CSR -> permuted row), endS
__global__ __launch_bounds__(256) void scatter_kernel(const int* __restrict__ endi, const int* __restrict__ srt,
                                                      int* __restrict__ curE, int* __restrict__ curS,
                                                      int* __restrict__ rankE, int* __restrict__ srtE,
                                                      int* __restrict__ listS2, int* __restrict__ endS){
  for (int i = blockIdx.x*256 + threadIdx.x; i < NE; i += gridDim.x*256){
    const int e = endi[i], s = srt[i];
    int p = atomicAdd(&curE[e], 1);
    rankE[i] = p; srtE[p] = s;
    int q = atomicAdd(&curS[s], 1);
    listS2[q] = p; endS[q] = e;
  }
}

// Wb0: natural K padded 160. Wb1/Wbm: K permuted by cpi. bp0/bp1: biases permuted by cpi.
__global__ __launch_bounds__(256) void convertW_kernel(const float* __restrict__ W1, const float* __restrict__ W0,
                                                       const float* __restrict__ Wm,
                                                       const float* __restrict__ b0, const float* __restrict__ b1,
                                                       u16* __restrict__ Wb1, u16* __restrict__ Wb0,
                                                       u16* __restrict__ Wbm,
                                                       float* __restrict__ bp0, float* __restrict__ bp1){
  int i = blockIdx.x*256 + threadIdx.x;
  if (i < 128*128){
    int j = i >> 7, k = i & 127;
    Wb1[i] = f2bf(W1[j*DH + cpi(k)]);
    Wbm[i] = f2bf(Wm[j*DH + cpi(k)]);
  }
  if (i < 128*160){
    int j = i/160, k = i - j*160;
    Wb0[i] = (k < KE) ? f2bf(W0[j*KE + k]) : (u16)0;
  }
  if (i < 128){ bp0[i] = b0[cpi(i)]; bp1[i] = b1[cpi(i)]; }
}

// ================= layer 0: h'[rankE[e]] = lrelu(cf[e] @ W0^T + b), 64-row tile =================
__global__ __launch_bounds__(256) void layer0_mfma(const float* __restrict__ cf, const u16* __restrict__ Wb0,
                                                   const float* __restrict__ bp0, const int* __restrict__ rankE,
                                                   u16* __restrict__ h){
  __shared__ __align__(16) u16 As[64*168];    // 21,504 B
  const int t = threadIdx.x, lane = t & 63, wv = t >> 6;
  const int wr = wv >> 1, wc = wv & 1;
  const int e0 = blockIdx.x * 64;
  const int q = lane & 15, kg8 = (lane >> 4)*8;

  bf16x8 bfrag[5][4];
  #pragma unroll
  for (int fc = 0; fc < 4; ++fc)
    #pragma unroll
    for (int ks = 0; ks < 5; ++ks)
      bfrag[ks][fc] = *(const bf16x8*)&Wb0[(size_t)(wc*64 + fc*16 + q)*160 + ks*32 + kg8];

  {
    const float4* src = (const float4*)(cf + (size_t)e0*KE);
    #pragma unroll
    for (int k = 0; k < 10; ++k){
      const int i4 = t + k*256;
      if (i4 < 2352){
        float4 v = src[i4];
        const int g = i4*4;
        int r = (unsigned)g / 147u;
        int c = g - r*147;
        u16 w0 = f2bf(v.x), w1 = f2bf(v.y), w2 = f2bf(v.z), w3 = f2bf(v.w);
        As[r*168 + c] = w0; if (++c == 147){ c = 0; ++r; }
        As[r*168 + c] = w1; if (++c == 147){ c = 0; ++r; }
        As[r*168 + c] = w2; if (++c == 147){ c = 0; ++r; }
        As[r*168 + c] = w3;
      }
    }
  }
  for (int idx = t; idx < 64*16; idx += 256){
    const int r = idx >> 4, c = idx & 15;
    if (c < 13) As[r*168 + 147 + c] = 0;
  }
  __syncthreads();

  f32x4 acc[2][4];
  #pragma unroll
  for (int fr = 0; fr < 2; ++fr)
    #pragma unroll
    for (int fc = 0; fc < 4; ++fc){ acc[fr][fc][0]=0.f; acc[fr][fc][1]=0.f; acc[fr][fc][2]=0.f; acc[fr][fc][3]=0.f; }
  #pragma unroll
  for (int ks = 0; ks < 5; ++ks){
    bf16x8 a[2];
    #pragma unroll
    for (int fr = 0; fr < 2; ++fr)
      a[fr] = *(const bf16x8*)&As[(wr*32 + fr*16 + q)*168 + ks*32 + kg8];
    #pragma unroll
    for (int fr = 0; fr < 2; ++fr)
      #pragma unroll
      for (int fc = 0; fc < 4; ++fc)
        acc[fr][fc] = __builtin_amdgcn_mfma_f32_16x16x32_bf16(a[fr], bfrag[ks][fc], acc[fr][fc], 0, 0, 0);
  }

  const float4 bb = *(const float4*)&bp0[wc*64 + q*4];
  #pragma unroll
  for (int fr = 0; fr < 2; ++fr){
    #pragma unroll
    for (int r = 0; r < 4; ++r){
      const int ee = e0 + wr*32 + fr*16 + (lane>>4)*4 + r;
      const int row = rankE[ee];
      ushort4 o;
      o.x = f2bf(lrelu(acc[fr][0][r] + bb.x));
      o.y = f2bf(lrelu(acc[fr][1][r] + bb.y));
      o.z = f2bf(lrelu(acc[fr][2][r] + bb.z));
      o.w = f2bf(lrelu(acc[fr][3][r] + bb.w));
      *(ushort4*)&h[(size_t)row*DH + wc*64 + q*4] = o;
    }
  }
}

// ================= agg[n] = sum of h' rows [offE[n], offE[n+1]) — 2 waves/node, 8-edge ILP =====
__global__ __launch_bounds__(256) void aggE_kernel(const u16* __restrict__ h, const int* __restrict__ off,
                                                   float* __restrict__ agg){
  const int t = threadIdx.x, lane = t & 63, wv = t >> 6;
  const int n = blockIdx.x*2 + (wv >> 1);
  const int half = wv & 1;
  const int lo = off[n], hi = off[n+1];
  const int c8 = half*64 + (lane & 7)*8, sub = lane >> 3;
  float a0=0,a1=0,a2=0,a3=0,a4=0,a5=0,a6=0,a7=0;
  for (int i = lo + sub; i < hi; i += 8){
    uint4 hv = *(const uint4*)&h[(size_t)i*DH + c8];
    a0 += bflo(hv.x); a1 += bfhi(hv.x); a2 += bflo(hv.y); a3 += bfhi(hv.y);
    a4 += bflo(hv.z); a5 += bfhi(hv.z); a6 += bflo(hv.w); a7 += bfhi(hv.w);
  }
  a0 += __shfl_xor(a0,8);  a1 += __shfl_xor(a1,8);  a2 += __shfl_xor(a2,8);  a3 += __shfl_xor(a3,8);
  a4 += __shfl_xor(a4,8);  a5 += __shfl_xor(a5,8);  a6 += __shfl_xor(a6,8);  a7 += __shfl_xor(a7,8);
  a0 += __shfl_xor(a0,16); a1 += __shfl_xor(a1,16); a2 += __shfl_xor(a2,16); a3 += __shfl_xor(a3,16);
  a4 += __shfl_xor(a4,16); a5 += __shfl_xor(a5,16); a6 += __shfl_xor(a6,16); a7 += __shfl_xor(a7,16);
  a0 += __shfl_xor(a0,32); a1 += __shfl_xor(a1,32); a2 += __shfl_xor(a2,32); a3 += __shfl_xor(a3,32);
  a4 += __shfl_xor(a4,32); a5 += __shfl_xor(a5,32); a6 += __shfl_xor(a6,32); a7 += __shfl_xor(a7,32);
  if (sub == 0){
    *(float4*)&agg[(size_t)n*DH + c8]     = make_float4(a0,a1,a2,a3);
    *(float4*)&agg[(size_t)n*DH + c8 + 4] = make_float4(a4,a5,a6,a7);
  }
}

// ========== P/Q GEMM: P = bf16(agg@W^T + b) ; Q = bf16(h'[rankE[0:N]]@W^T)  (pi space, bf16 out) =====
__global__ __launch_bounds__(256) void pq_gemm(const float* __restrict__ agg, const u16* __restrict__ h,
                                               const int* __restrict__ rankE, const u16* __restrict__ Wb1,
                                               const float* __restrict__ bp1, u16* __restrict__ P,
                                               u16* __restrict__ Q){
  __shared__ u16 Alds[128][136];
  const int t = threadIdx.x, lane = t & 63, wv = t >> 6;
  const int wr = wv >> 1, wc = wv & 1;
  const int r0 = blockIdx.x * 128;
  const int q = lane & 15, kg8 = (lane >> 4)*8;

  bf16x8 bfrag[4][4];
  #pragma unroll
  for (int fc = 0; fc < 4; ++fc)
    #pragma unroll
    for (int ks = 0; ks < 4; ++ks)
      bfrag[ks][fc] = *(const bf16x8*)&Wb1[(size_t)(wc*64 + fc*16 + q)*128 + ks*32 + kg8];

  {
    const int rt = t >> 1, half = t & 1;
    const int gr = r0 + rt;
    u16* dst = &Alds[rt][half*64];
    if (gr < NN){
      const float4* src = (const float4*)&agg[(size_t)gr*DH + half*64];
      #pragma unroll
      for (int p = 0; p < 16; ++p){
        float4 x = src[p];
        ushort4 o; o.x=f2bf(x.x); o.y=f2bf(x.y); o.z=f2bf(x.z); o.w=f2bf(x.w);
        *(ushort4*)&dst[p*4] = o;
      }
    } else if (gr < 2*NN){
      const int row = rankE[gr - NN];
      const ushort4* src = (const ushort4*)&h[(size_t)row*DH + half*64];
      #pragma unroll
      for (int p = 0; p < 16; ++p) *(ushort4*)&dst[p*4] = src[p];
    } else {
      ushort4 z; z.x=0; z.y=0; z.z=0; z.w=0;
      #pragma unroll
      for (int p = 0; p < 16; ++p) *(ushort4*)&dst[p*4] = z;
    }
  }
  __syncthreads();

  f32x4 acc[4][4];
  #pragma unroll
  for (int fr = 0; fr < 4; ++fr)
    #pragma unroll
    for (int fc = 0; fc < 4; ++fc){ acc[fr][fc][0]=0.f; acc[fr][fc][1]=0.f; acc[fr][fc][2]=0.f; acc[fr][fc][3]=0.f; }
  #pragma unroll
  for (int ks = 0; ks < 4; ++ks){
    bf16x8 a[4];
    #pragma unroll
    for (int fr = 0; fr < 4; ++fr)
      a[fr] = *(const bf16x8*)&Alds[wr*64 + fr*16 + q][ks*32 + kg8];
    #pragma unroll
    for (int fr = 0; fr < 4; ++fr)
      #pragma unroll
      for (int fc = 0; fc < 4; ++fc)
        acc[fr][fc] = __builtin_amdgcn_mfma_f32_16x16x32_bf16(a[fr], bfrag[ks][fc], acc[fr][fc], 0, 0, 0);
  }

  const float4 bb = *(const float4*)&bp1[wc*64 + q*4];
  #pragma unroll
  for (int fr = 0; fr < 4; ++fr){
    #pragma unroll
    for (int r = 0; r < 4; ++r){
      const int grow = r0 + wr*64 + fr*16 + (lane>>4)*4 + r;
      if (grow < NN){
        ushort4 o;
        o.x = f2bf(acc[fr][0][r] + bb.x);
        o.y = f2bf(acc[fr][1][r] + bb.y);
        o.z = f2bf(acc[fr][2][r] + bb.z);
        o.w = f2bf(acc[fr][3][r] + bb.w);
        *(ushort4*)&P[(size_t)grow*DH + wc*64 + q*4] = o;
      } else if (grow < 2*NN){
        ushort4 o;
        o.x = f2bf(acc[fr][0][r]);
        o.y = f2bf(acc[fr][1][r]);
        o.z = f2bf(acc[fr][2][r]);
        o.w = f2bf(acc[fr][3][r]);
        *(ushort4*)&Q[(size_t)(grow-NN)*DH + wc*64 + q*4] = o;
      }
    }
  }
}

// ========== layer-3 P/Q GEMM: head rows h2 computed on the fly (h2 = lrelu(h1 + P2[srt] - Q2[end])) =====
__global__ __launch_bounds__(256) void pq_gemm3(const float* __restrict__ agg, const u16* __restrict__ h1,
                                                const int* __restrict__ rankE, const int* __restrict__ srt,
                                                const int* __restrict__ endi,
                                                const u16* __restrict__ P2, const u16* __restrict__ Q2,
                                                const u16* __restrict__ Wb1, const float* __restrict__ bp1,
                                                u16* __restrict__ P, u16* __restrict__ Q){
  __shared__ u16 Alds[128][136];
  const int t = threadIdx.x, lane = t & 63, wv = t >> 6;
  const int wr = wv >> 1, wc = wv & 1;
  const int r0 = blockIdx.x * 128;
  const int q = lane & 15, kg8 = (lane >> 4)*8;

  bf16x8 bfrag[4][4];
  #pragma unroll
  for (int fc = 0; fc < 4; ++fc)
    #pragma unroll
    for (int ks = 0; ks < 4; ++ks)
      bfrag[ks][fc] = *(const bf16x8*)&Wb1[(size_t)(wc*64 + fc*16 + q)*128 + ks*32 + kg8];

  {
    const int rt = t >> 1, half = t & 1;
    const int gr = r0 + rt;
    u16* dst = &Alds[rt][half*64];
    if (gr < NN){
      const float4* src = (const float4*)&agg[(size_t)gr*DH + half*64];
      #pragma unroll
      for (int p = 0; p < 16; ++p){
        float4 x = src[p];
        ushort4 o; o.x=f2bf(x.x); o.y=f2bf(x.y); o.z=f2bf(x.z); o.w=f2bf(x.w);
        *(ushort4*)&dst[p*4] = o;
      }
    } else if (gr < 2*NN){
      const int e = gr - NN;
      const int row = rankE[e], s = srt[e], d = endi[e];
      const ushort4* hsrc = (const ushort4*)&h1[(size_t)row*DH + half*64];
      const ushort4* psrc = (const ushort4*)&P2[(size_t)s*DH + half*64];
      const ushort4* qsrc = (const ushort4*)&Q2[(size_t)d*DH + half*64];
      #pragma unroll
      for (int p = 0; p < 16; ++p){
        ushort4 hv = hsrc[p], pv = psrc[p], qv = qsrc[p];
        ushort4 o;
        o.x = f2bf(lrelu(bf2f(hv.x) + bf2f(pv.x) - bf2f(qv.x)));
        o.y = f2bf(lrelu(bf2f(hv.y) + bf2f(pv.y) - bf2f(qv.y)));
        o.z = f2bf(lrelu(bf2f(hv.z) + bf2f(pv.z) - bf2f(qv.z)));
        o.w = f2bf(lrelu(bf2f(hv.w) + bf2f(pv.w) - bf2f(qv.w)));
        *(ushort4*)&dst[p*4] = o;
      }
    } else {
      ushort4 z; z.x=0; z.y=0; z.z=0; z.w=0;
      #pragma unroll
      for (int p = 0; p < 16; ++p) *(ushort4*)&dst[p*4] = z;
    }
  }
  __syncthreads();

  f32x4 acc[4][4];
  #pragma unroll
  for (int fr = 0; fr < 4; ++fr)
    #pragma unroll
    for (int fc = 0; fc < 4; ++fc){ acc[fr][fc][0]=0.f; acc[fr][fc][1]=0.f; acc[fr][fc][2]=0.f; acc[fr][fc][3]=0.f; }
  #pragma unroll
  for (int ks = 0; ks < 4; ++ks){
    bf16x8 a[4];
    #pragma unroll
    for (int fr = 0; fr < 4; ++fr)
      a[fr] = *(const bf16x8*)&Alds[wr*64 + fr*16 + q][ks*32 + kg8];
    #pragma unroll
    for (int fr = 0; fr < 4; ++fr)
      #pragma unroll
      for (int fc = 0; fc < 4; ++fc)
        acc[fr][fc] = __builtin_amdgcn_mfma_f32_16x16x32_bf16(a[fr], bfrag[ks][fc], acc[fr][fc], 0, 0, 0);
  }

  const float4 bb = *(const float4*)&bp1[wc*64 + q*4];
  #pragma unroll
  for (int fr = 0; fr < 4; ++fr){
    #pragma unroll
    for (int r = 0; r < 4; ++r){
      const int grow = r0 + wr*64 + fr*16 + (lane>>4)*4 + r;
      if (grow < NN){
        ushort4 o;
        o.x = f2bf(acc[fr][0][r] + bb.x);
        o.y = f2bf(acc[fr][1][r] + bb.y);
        o.z = f2bf(acc[fr][2][r] + bb.z);
        o.w = f2bf(acc[fr][3][r] + bb.w);
        *(ushort4*)&P[(size_t)grow*DH + wc*64 + q*4] = o;
      } else if (grow < 2*NN){
        ushort4 o;
        o.x = f2bf(acc[fr][0][r]);
        o.y = f2bf(acc[fr][1][r]);
        o.z = f2bf(acc[fr][2][r]);
        o.w = f2bf(acc[fr][3][r]);
        *(ushort4*)&Q[(size_t)(grow-NN)*DH + wc*64 + q*4] = o;
      }
    }
  }
}

// ===== layer 1: h'[i] = lrelu(h'[i] + P[srtE[i]] - Q[n]); agg[n]=sum — writes h =====
__global__ __launch_bounds__(256) void fused_mid(u16* __restrict__ h, const u16* __restrict__ P,
                                                 const u16* __restrict__ Q, const int* __restrict__ srtE,
                                                 const int* __restrict__ off, float* __restrict__ agg){
  const int t = threadIdx.x, lane = t & 63, wv = t >> 6;
  const int n = blockIdx.x*2 + (wv >> 1);
  const int half = wv & 1;
  const int lo = off[n], hi = off[n+1];
  const int c8 = half*64 + (lane & 7)*8, sub = lane >> 3;
  const uint4 qw = *(const uint4*)&Q[(size_t)n*DH + c8];
  const float q0 = bflo(qw.x), q1 = bfhi(qw.x), q2 = bflo(qw.y), q3 = bfhi(qw.y);
  const float q4 = bflo(qw.z), q5 = bfhi(qw.z), q6 = bflo(qw.w), q7 = bfhi(qw.w);
  float a0=0,a1=0,a2=0,a3=0,a4=0,a5=0,a6=0,a7=0;
  for (int i = lo + sub; i < hi; i += 8){
    const int s = srtE[i];
    uint4 hv = *(const uint4*)&h[(size_t)i*DH + c8];
    uint4 pw = *(const uint4*)&P[(size_t)s*DH + c8];
    float v0 = lrelu(bflo(hv.x) + bflo(pw.x) - q0);
    float v1 = lrelu(bfhi(hv.x) + bfhi(pw.x) - q1);
    float v2 = lrelu(bflo(hv.y) + bflo(pw.y) - q2);
    float v3 = lrelu(bfhi(hv.y) + bfhi(pw.y) - q3);
    float v4 = lrelu(bflo(hv.z) + bflo(pw.z) - q4);
    float v5 = lrelu(bfhi(hv.z) + bfhi(pw.z) - q5);
    float v6 = lrelu(bflo(hv.w) + bflo(pw.w) - q6);
    float v7 = lrelu(bfhi(hv.w) + bfhi(pw.w) - q7);
    uint4 o;
    o.x = pk2(v0, v1); o.y = pk2(v2, v3); o.z = pk2(v4, v5); o.w = pk2(v6, v7);
    *(uint4*)&h[(size_t)i*DH + c8] = o;
    a0+=v0; a1+=v1; a2+=v2; a3+=v3; a4+=v4; a5+=v5; a6+=v6; a7+=v7;
  }
  a0 += __shfl_xor(a0,8);  a1 += __shfl_xor(a1,8);  a2 += __shfl_xor(a2,8);  a3 += __shfl_xor(a3,8);
  a4 += __shfl_xor(a4,8);  a5 += __shfl_xor(a5,8);  a6 += __shfl_xor(a6,8);  a7 += __shfl_xor(a7,8);
  a0 += __shfl_xor(a0,16); a1 += __shfl_xor(a1,16); a2 += __shfl_xor(a2,16); a3 += __shfl_xor(a3,16);
  a4 += __shfl_xor(a4,16); a5 += __shfl_xor(a5,16); a6 += __shfl_xor(a6,16); a7 += __shfl_xor(a7,16);
  a0 += __shfl_xor(a0,32); a1 += __shfl_xor(a1,32); a2 += __shfl_xor(a2,32); a3 += __shfl_xor(a3,32);
  a4 += __shfl_xor(a4,32); a5 += __shfl_xor(a5,32); a6 += __shfl_xor(a6,32); a7 += __shfl_xor(a7,32);
  if (sub == 0){
    *(float4*)&agg[(size_t)n*DH + c8]     = make_float4(a0,a1,a2,a3);
    *(float4*)&agg[(size_t)n*DH + c8 + 4] = make_float4(a4,a5,a6,a7);
  }
}

// ===== layer 2: agg[n] = Σ lrelu(h1[i] + P[srtE[i]] - Q[n]) — NO h write =====
__global__ __launch_bounds__(256) void fused_mid_nw(const u16* __restrict__ h, const u16* __restrict__ P,
                                                    const u16* __restrict__ Q, const int* __restrict__ srtE,
                                                    const int* __restrict__ off, float* __restrict__ agg){
  const int t = threadIdx.x, lane = t & 63, wv = t >> 6;
  const int n = blockIdx.x*2 + (wv >> 1);
  const int half = wv & 1;
  const int lo = off[n], hi = off[n+1];
  const int c8 = half*64 + (lane & 7)*8, sub = lane >> 3;
  const uint4 qw = *(const uint4*)&Q[(size_t)n*DH + c8];
  const float q0 = bflo(qw.x), q1 = bfhi(qw.x), q2 = bflo(qw.y), q3 = bfhi(qw.y);
  const float q4 = bflo(qw.z), q5 = bfhi(qw.z), q6 = bflo(qw.w), q7 = bfhi(qw.w);
  float a0=0,a1=0,a2=0,a3=0,a4=0,a5=0,a6=0,a7=0;
  for (int i = lo + sub; i < hi; i += 8){
    const int s = srtE[i];
    uint4 hv = *(const uint4*)&h[(size_t)i*DH + c8];
    uint4 pw = *(const uint4*)&P[(size_t)s*DH + c8];
    a0 += lrelu(bflo(hv.x) + bflo(pw.x) - q0);
    a1 += lrelu(bfhi(hv.x) + bfhi(pw.x) - q1);
    a2 += lrelu(bflo(hv.y) + bflo(pw.y) - q2);
    a3 += lrelu(bfhi(hv.y) + bfhi(pw.y) - q3);
    a4 += lrelu(bflo(hv.z) + bflo(pw.z) - q4);
    a5 += lrelu(bfhi(hv.z) + bfhi(pw.z) - q5);
    a6 += lrelu(bflo(hv.w) + bflo(pw.w) - q6);
    a7 += lrelu(bfhi(hv.w) + bfhi(pw.w) - q7);
  }
  a0 += __shfl_xor(a0,8);  a1 += __shfl_xor(a1,8);  a2 += __shfl_xor(a2,8);  a3 += __shfl_xor(a3,8);
  a4 += __shfl_xor(a4,8);  a5 += __shfl_xor(a5,8);  a6 += __shfl_xor(a6,8);  a7 += __shfl_xor(a7,8);
  a0 += __shfl_xor(a0,16); a1 += __shfl_xor(a1,16); a2 += __shfl_xor(a2,16); a3 += __shfl_xor(a3,16);
  a4 += __shfl_xor(a4,16); a5 += __shfl_xor(a5,16); a6 += __shfl_xor(a6,16); a7 += __shfl_xor(a7,16);
  a0 += __shfl_xor(a0,32); a1 += __shfl_xor(a1,32); a2 += __shfl_xor(a2,32); a3 += __shfl_xor(a3,32);
  a4 += __shfl_xor(a4,32); a5 += __shfl_xor(a5,32); a6 += __shfl_xor(a6,32); a7 += __shfl_xor(a7,32);
  if (sub == 0){
    *(float4*)&agg[(size_t)n*DH + c8]     = make_float4(a0,a1,a2,a3);
    *(float4*)&agg[(size_t)n*DH + c8 + 4] = make_float4(a4,a5,a6,a7);
  }
}

// ===== layer 3: hnode[s] = Σ lrelu( lrelu(h1[row]+P2[s]-Q2[d]) + P3[s] - Q3[d] ), srt-CSR =====
__global__ __launch_bounds__(256) void fused_last3(const u16* __restrict__ h1,
                                                   const u16* __restrict__ P2, const u16* __restrict__ Q2,
                                                   const u16* __restrict__ P3, const u16* __restrict__ Q3,
                                                   const int* __restrict__ endS, const int* __restrict__ listS2,
                                                   const int* __restrict__ off, float* __restrict__ hnode){
  const int t = threadIdx.x, lane = t & 63, wv = t >> 6;
  const int s = blockIdx.x*2 + (wv >> 1);
  const int half = wv & 1;
  const int lo = off[s], hi = off[s+1];
  const int c8 = half*64 + (lane & 7)*8, sub = lane >> 3;
  const uint4 p2w = *(const uint4*)&P2[(size_t)s*DH + c8];
  const uint4 p3w = *(const uint4*)&P3[(size_t)s*DH + c8];
  const float p20 = bflo(p2w.x), p21 = bfhi(p2w.x), p22 = bflo(p2w.y), p23 = bfhi(p2w.y);
  const float p24 = bflo(p2w.z), p25 = bfhi(p2w.z), p26 = bflo(p2w.w), p27 = bfhi(p2w.w);
  const float p30 = bflo(p3w.x), p31 = bfhi(p3w.x), p32 = bflo(p3w.y), p33 = bfhi(p3w.y);
  const float p34 = bflo(p3w.z), p35 = bfhi(p3w.z), p36 = bflo(p3w.w), p37 = bfhi(p3w.w);
  float a0=0,a1=0,a2=0,a3=0,a4=0,a5=0,a6=0,a7=0;
  for (int i = lo + sub; i < hi; i += 8){
    const int row = listS2[i];
    const int d = endS[i];
    uint4 hv = *(const uint4*)&h1[(size_t)row*DH + c8];
    uint4 q2w = *(const uint4*)&Q2[(size_t)d*DH + c8];
    uint4 q3w = *(const uint4*)&Q3[(size_t)d*DH + c8];
    float t0 = lrelu(bflo(hv.x) + p20 - bflo(q2w.x));
    float t1 = lrelu(bfhi(hv.x) + p21 - bfhi(q2w.x));
    float t2 = lrelu(bflo(hv.y) + p22 - bflo(q2w.y));
    float t3 = lrelu(bfhi(hv.y) + p23 - bfhi(q2w.y));
    float t4 = lrelu(bflo(hv.z) + p24 - bflo(q2w.z));
    float t5 = lrelu(bfhi(hv.z) + p25 - bfhi(q2w.z));
    float t6 = lrelu(bflo(hv.w) + p26 - bflo(q2w.w));
    float t7 = lrelu(bfhi(hv.w) + p27 - bfhi(q2w.w));
    a0 += lrelu(t0 + p30 - bflo(q3w.x));
    a1 += lrelu(t1 + p31 - bfhi(q3w.x));
    a2 += lrelu(t2 + p32 - bflo(q3w.y));
    a3 += lrelu(t3 + p33 - bfhi(q3w.y));
    a4 += lrelu(t4 + p34 - bflo(q3w.z));
    a5 += lrelu(t5 + p35 - bfhi(q3w.z));
    a6 += lrelu(t6 + p36 - bflo(q3w.w));
    a7 += lrelu(t7 + p37 - bfhi(q3w.w));
  }
  a0 += __shfl_xor(a0,8);  a1 += __shfl_xor(a1,8);  a2 += __shfl_xor(a2,8);  a3 += __shfl_xor(a3,8);
  a4 += __shfl_xor(a4,8);  a5 += __shfl_xor(a5,8);  a6 += __shfl_xor(a6,8);  a7 += __shfl_xor(a7,8);
  a0 += __shfl_xor(a0,16); a1 += __shfl_xor(a1,16); a2 += __shfl_xor(a2,16); a3 += __shfl_xor(a3,16);
  a4 += __shfl_xor(a4,16); a5 += __shfl_xor(a5,16); a6 += __shfl_xor(a6,16); a7 += __shfl_xor(a7,16);
  a0 += __shfl_xor(a0,32); a1 += __shfl_xor(a1,32); a2 += __shfl_xor(a2,32); a3 += __shfl_xor(a3,32);
  a4 += __shfl_xor(a4,32); a5 += __shfl_xor(a5,32); a6 += __shfl_xor(a6,32); a7 += __shfl_xor(a7,32);
  if (sub == 0){
    *(float4*)&hnode[(size_t)s*DH + c8]     = make_float4(a0,a1,a2,a3);
    *(float4*)&hnode[(size_t)s*DH + c8 + 4] = make_float4(a4,a5,a6,a7);
  }
}

// ===== nodes (MFMA): atom = lrelu(hnode @ Wmol^T + b_mol); hg[batch] += atom/||atom|| =====
__global__ __launch_bounds__(256) void node_mfma(const float* __restrict__ hn, const u16* __restrict__ Wbm,
                                                 const float* __restrict__ bm, const int* __restrict__ batch,
                                                 float* __restrict__ atom, float* __restrict__ hg){
  __shared__ u16 Alds[128][136];
  __shared__ float ssb[128];
  const int t = threadIdx.x, lane = t & 63, wv = t >> 6;
  const int wr = wv >> 1, wc = wv & 1;
  const int r0 = blockIdx.x * 128;
  const int q = lane & 15, kg8 = (lane >> 4)*8;

  bf16x8 bfrag[4][4];
  #pragma unroll
  for (int fc = 0; fc < 4; ++fc)
    #pragma unroll
    for (int ks = 0; ks < 4; ++ks)
      bfrag[ks][fc] = *(const bf16x8*)&Wbm[(size_t)(wc*64 + fc*16 + q)*128 + ks*32 + kg8];

  {
    const int rt = t >> 1, half = t & 1;
    const int gr = r0 + rt;
    u16* dst = &Alds[rt][half*64];
    if (gr < NN){
      const float4* src = (const float4*)&hn[(size_t)gr*DH + half*64];
      #pragma unroll
      for (int p = 0; p < 16; ++p){
        float4 x = src[p];
        ushort4 o; o.x=f2bf(x.x); o.y=f2bf(x.y); o.z=f2bf(x.z); o.w=f2bf(x.w);
        *(ushort4*)&dst[p*4] = o;
      }
    } else {
      ushort4 z; z.x=0; z.y=0; z.z=0; z.w=0;
      #pragma unroll
      for (int p = 0; p < 16; ++p) *(ushort4*)&dst[p*4] = z;
    }
  }
  if (t < 128) ssb[t] = 0.f;
  __syncthreads();

  f32x4 acc[4][4];
  #pragma unroll
  for (int fr = 0; fr < 4; ++fr)
    #pragma unroll
    for (int fc = 0; fc < 4; ++fc){ acc[fr][fc][0]=0.f; acc[fr][fc][1]=0.f; acc[fr][fc][2]=0.f; acc[fr][fc][3]=0.f; }
  #pragma unroll
  for (int ks = 0; ks < 4; ++ks){
    bf16x8 a[4];
    #pragma unroll
    for (int fr = 0; fr < 4; ++fr)
      a[fr] = *(const bf16x8*)&Alds[wr*64 + fr*16 + q][ks*32 + kg8];
    #pragma unroll
    for (int fr = 0; fr < 4; ++fr)
      #pragma unroll
      for (int fc = 0; fc < 4; ++fc)
        acc[fr][fc] = __builtin_amdgcn_mfma_f32_16x16x32_bf16(a[fr], bfrag[ks][fc], acc[fr][fc], 0, 0, 0);
  }

  float bmv[4];
  #pragma unroll
  for (int fc = 0; fc < 4; ++fc) bmv[fc] = bm[wc*64 + fc*16 + q];

  float sp[4][4];
  #pragma unroll
  for (int fr = 0; fr < 4; ++fr)
    #pragma unroll
    for (int r = 0; r < 4; ++r){
      float s2 = 0.f;
      #pragma unroll
      for (int fc = 0; fc < 4; ++fc){
        float v = lrelu(acc[fr][fc][r] + bmv[fc]);
        acc[fr][fc][r] = v;
        s2 += v*v;
      }
      sp[fr][r] = s2;
    }
  #pragma unroll
  for (int m = 1; m <= 8; m <<= 1)
    #pragma unroll
    for (int fr = 0; fr < 4; ++fr)
      #pragma unroll
      for (int r = 0; r < 4; ++r)
        sp[fr][r] += __shfl_xor(sp[fr][r], m);
  if ((lane & 15) == 0){
    #pragma unroll
    for (int fr = 0; fr < 4; ++fr)
      #pragma unroll
      for (int r = 0; r < 4; ++r)
        atomicAdd(&ssb[wr*64 + fr*16 + (lane>>4)*4 + r], sp[fr][r]);
  }
  __syncthreads();

  #pragma unroll
  for (int fr = 0; fr < 4; ++fr){
    #pragma unroll
    for (int r = 0; r < 4; ++r){
      const int lrow = wr*64 + fr*16 + (lane>>4)*4 + r;
      const int grow = r0 + lrow;
      if (grow < NN){
        const float inv = 1.f / fmaxf(sqrtf(ssb[lrow]), 1e-12f);
        const int g = batch[grow];
        #pragma unroll
        for (int fc = 0; fc < 4; ++fc){
          const int col = wc*64 + fc*16 + q;
          const float v = acc[fr][fc][r];
          atom[(size_t)grow*DH + col] = v;
          atomicAdd(&hg[(size_t)g*DH + col], v*inv);
        }
      }
    }
  }
}

// ================= out GEMV over hg =================
__global__ __launch_bounds__(128) void out_gemv(const float* __restrict__ hg, const float* __restrict__ Wo,
                                                const float* __restrict__ bo, float* __restrict__ out){
  const int g = blockIdx.x, t = threadIdx.x;
  float v = hg[(size_t)g*DH + t] * Wo[t];
  #pragma unroll
  for (int d2 = 1; d2 < 64; d2 <<= 1) v += __shfl_xor(v, d2);
  __shared__ float red[2];
  if ((t & 63) == 0) red[t >> 6] = v;
  __syncthreads();
  if (t == 0) out[g] = red[0] + red[1] + bo[0];
}

extern "C" void kernel_launch(void* const* d_in, const int* in_sizes, int n_in,
                              void* d_out, int out_size, void* d_ws, size_t ws_size,
                              hipStream_t stream)
{
  const float* cf     = (const float*)d_in[1];
  const int*   srt    = (const int*)d_in[2];
  const int*   endi   = (const int*)d_in[3];
  const int*   batch  = (const int*)d_in[5];
  const float* W_init = (const float*)d_in[6];
  const float* b_init = (const float*)d_in[7];
  const float* W_h1   = (const float*)d_in[8];
  const float* b_h1   = (const float*)d_in[9];
  const float* W_mol  = (const float*)d_in[10];
  const float* b_mol  = (const float*)d_in[11];
  const float* W_out  = (const float*)d_in[12];
  const float* b_out  = (const float*)d_in[13];

  float* out  = (float*)d_out;
  float* atom = out + NG;

  char* ws = (char*)d_ws;
  u16*   h      = (u16*)(ws);                    // 256,000,000 B (end-CSR rows, pi cols)
  float* agg    = (float*)(ws + 256000000);      // 25,600,000 B (pi cols)
  u16*   Pa     = (u16*)(ws + 281600000);        // 12,800,000 B (P1 / P3)
  u16*   Qa     = (u16*)(ws + 294400000);        // 12,800,000 B (Q1 / Q3)
  u16*   Pb     = (u16*)(ws + 307200000);        // 12,800,000 B (P2)
  u16*   Qb     = (u16*)(ws + 320000000);        // 12,800,000 B (Q2)
  int*   srtE   = (int*)(ws + 332800000);        // 4,000,000 B
  int*   endS   = (int*)(ws + 336800000);        // 4,000,000 B
  int*   rankE  = (int*)(ws + 340800000);        // 4,000,000 B
  int*   listS2 = (int*)(ws + 344800000);        // 4,000,000 B
  int*   offE   = (int*)(ws + 348800000);        // 200,704 B
  int*   offS   = (int*)(ws + 349000704);        // 200,704 B
  int*   curE   = (int*)(ws + 349201408);        // 200,704 B
  int*   curS   = (int*)(ws + 349402112);        // 200,704 B
  u16*   Wb1    = (u16*)(ws + 349602816);        // 32,768 B
  u16*   Wb0    = (u16*)(ws + 349635584);        // 40,960 B
  u16*   Wbm    = (u16*)(ws + 349676544);        // 32,768 B
  float* bp0    = (float*)(ws + 349709312);      // 512 B
  float* bp1    = (float*)(ws + 349709824);      // 512 B
  float* hg     = (float*)(ws + 349710336);      // 512,000 B
  float* hnode  = agg;                           // agg2 dead after pq_gemm3

  // ---- CSR build (int atomics only)
  hipMemsetAsync(curE, 0, 200704, stream);
  hipMemsetAsync(curS, 0, 200704, stream);
  hipMemsetAsync(hg, 0, (size_t)NG*DH*4, stream);
  hist_kernel<<<1024, 256, 0, stream>>>(endi, srt, curE, curS);
  scan2_kernel<<<2, 1024, 0, stream>>>(curE, offE, curS, offS);
  hipMemcpyAsync(curE, offE, (size_t)NN*4, hipMemcpyDeviceToDevice, stream);
  hipMemcpyAsync(curS, offS, (size_t)NN*4, hipMemcpyDeviceToDevice, stream);
  scatter_kernel<<<1024, 256, 0, stream>>>(endi, srt, curE, curS, rankE, srtE, listS2, endS);
  convertW_kernel<<<80, 256, 0, stream>>>(W_h1, W_init, W_mol, b_init, b_h1, Wb1, Wb0, Wbm, bp0, bp1);

  // ---- layer 0 (64-row tiles; writes h0 in end-CSR row order, pi col order) + agg0
  layer0_mfma<<<NE/64, 256, 0, stream>>>(cf, Wb0, bp0, rankE, h);
  aggE_kernel<<<NN/2, 256, 0, stream>>>(h, offE, agg);

  // ---- layer 1: P1/Q1 then fused update (writes h1 + agg1)
  pq_gemm<<<(2*NN + 127)/128, 256, 0, stream>>>(agg, h, rankE, Wb1, bp1, Pa, Qa);
  fused_mid<<<NN/2, 256, 0, stream>>>(h, Pa, Qa, srtE, offE, agg);

  // ---- layer 2: P2/Q2 then agg-only pass (NO h write)
  pq_gemm<<<(2*NN + 127)/128, 256, 0, stream>>>(agg, h, rankE, Wb1, bp1, Pb, Qb);
  fused_mid_nw<<<NN/2, 256, 0, stream>>>(h, Pb, Qb, srtE, offE, agg);

  // ---- layer 3: P3/Q3 (head h2 on the fly) then double-lrelu srt-CSR accumulation
  pq_gemm3<<<(2*NN + 127)/128, 256, 0, stream>>>(agg, h, rankE, srt, endi, Pb, Qb, Wb1, bp1, Pa, Qa);
  fused_last3<<<NN/2, 256, 0, stream>>>(h, Pb, Qb, Pa, Qa, endS, listS2, offS, hnode);

  // ---- node MLP (MFMA) + normalize + graph scatter, then out GEMV
  node_mfma<<<(NN + 127)/128, 256, 0, stream>>>(hnode, Wbm, b_mol, batch, atom, hg);
  out_gemv<<<NG, 128, 0, stream>>>(hg, W_out, b_out, out);
}